// Round 6
// baseline (301.569 us; speedup 1.0000x reference)
//
#include <hip/hip_runtime.h>
#include <hip/hip_bf16.h>
#include <stdint.h>

typedef unsigned short u16;
typedef unsigned int   u32;

#define S_LEN 2048
#define NQKV  3072
#define NH    32
#define NKV   8
#define SWIN  128
#define NEGV  (-1.0e9f)
#define SCALE_Q 0.35355339059327379f   // 64^-0.25

typedef __attribute__((ext_vector_type(4)))  float  f32x4;
typedef __attribute__((ext_vector_type(16))) float  f32x16;
typedef __attribute__((ext_vector_type(8)))  __bf16 bf16x8;

__device__ __forceinline__ u16 f2bf(float x){
  u32 u = __float_as_uint(x);
  return (u16)((u + 0x7fffu + ((u >> 16) & 1u)) >> 16);   // RNE
}
__device__ __forceinline__ float bf2f(u16 h){
  return __uint_as_float(((u32)h) << 16);
}
__device__ __forceinline__ void split2(float a, float b, u32& hw, u32& lw){
  u16 ha = f2bf(a), hb = f2bf(b);
  u16 la = f2bf(a - bf2f(ha)), lb = f2bf(b - bf2f(hb));
  hw = (u32)ha | ((u32)hb << 16);
  lw = (u32)la | ((u32)lb << 16);
}
__device__ __forceinline__ f32x4 mfma16(bf16x8 a, bf16x8 b, f32x4 c){
  return __builtin_amdgcn_mfma_f32_16x16x32_bf16(a, b, c, 0, 0, 0);
}
__device__ __forceinline__ f32x16 mfma32(bf16x8 a, bf16x8 b, f32x16 c){
  return __builtin_amdgcn_mfma_f32_32x32x16_bf16(a, b, c, 0, 0, 0);
}

typedef __attribute__((address_space(1))) const unsigned int ga_u32;
typedef __attribute__((address_space(3))) unsigned int       ls_u32;
__device__ __forceinline__ void gl16(const void* g, void* l){
  // direct global->LDS, 16B per lane; LDS dest = wave-uniform base + lane*16
  __builtin_amdgcn_global_load_lds((ga_u32*)g, (ls_u32*)l, 16, 0, 0);
}

// ---------------- prep: rope table [S][32][(cos,sin)] + packed bias[3072] ----
__global__ __launch_bounds__(256) void k_prep(const float* __restrict__ bq,
                                              const float* __restrict__ bk,
                                              const float* __restrict__ bv,
                                              float* __restrict__ ropetab,
                                              float* __restrict__ bias3){
  int id = blockIdx.x * 256 + threadIdx.x;        // S*32 threads
  int t = id >> 5, i = id & 31;
  float e = (i * 2.0f) / 64.0f;
  float base = (float)pow(150000.0, (double)e);
  float invf = 1.0f / base;
  float fr = (float)t * invf;
  ropetab[(size_t)id * 2 + 0] = cosf(fr);
  ropetab[(size_t)id * 2 + 1] = sinf(fr);
  if (id < NQKV){
    float b;
    if (id < 2048) b = bq[id];
    else if (id < 2560) b = bk[id - 2048];
    else b = bv[id - 2560];
    bias3[id] = b;
  }
}

// ---- pack A streaming: fp32 row-major -> hi/lo bf16 [M][K/8][8], SWIZZLED ---
// granule (r,p) stored at p' = (p&~3) | ((p&3) ^ ((r>>1)&3)).  Bijective within
// each aligned 4-packet group (same 64B line -> coalescing preserved).  The
// GEMM's LDS read applies the same XOR -> conflict-free ds_read_b128.
__global__ __launch_bounds__(256) void k_pack_a(const float* __restrict__ in,
                                                u16* __restrict__ oh, u16* __restrict__ ol,
                                                int n8){
  int id = blockIdx.x * 256 + threadIdx.x;
  if (id >= n8) return;
  int r = id >> 8, p = id & 255;              // P = 256 packets per row
  const float4* src = (const float4*)(in + (size_t)id * 8);
  float4 v0 = src[0], v1 = src[1];
  u32 hw[4], lw[4];
  split2(v0.x, v0.y, hw[0], lw[0]);
  split2(v0.z, v0.w, hw[1], lw[1]);
  split2(v1.x, v1.y, hw[2], lw[2]);
  split2(v1.z, v1.w, hw[3], lw[3]);
  int psw = (p & ~3) | ((p & 3) ^ ((r >> 1) & 3));
  size_t o = ((size_t)r * 256 + psw) * 8;
  *(uint4*)(oh + o) = make_uint4(hw[0], hw[1], hw[2], hw[3]);
  *(uint4*)(ol + o) = make_uint4(lw[0], lw[1], lw[2], lw[3]);
}

// ---------------- pack W: fp32 [K][N] (N contig) -> [K/8][NTot][8] at nOff ---
__global__ __launch_bounds__(256) void k_pack_w(const float* __restrict__ w,
                                                u16* __restrict__ oh, u16* __restrict__ ol,
                                                int K, int N, int NTot, int nOff){
  int id = blockIdx.x * 256 + threadIdx.x;
  int P = K >> 3;
  if (id >= P * N) return;
  int p = id / N, n = id % N;
  u32 hw[4], lw[4];
  #pragma unroll
  for (int j = 0; j < 4; ++j){
    float a = w[(size_t)(8 * p + 2 * j) * N + n];
    float b = w[(size_t)(8 * p + 2 * j + 1) * N + n];
    split2(a, b, hw[j], lw[j]);
  }
  size_t o = ((size_t)p * NTot + nOff + n) * 8;
  *(uint4*)(oh + o) = make_uint4(hw[0], hw[1], hw[2], hw[3]);
  *(uint4*)(ol + o) = make_uint4(lw[0], lw[1], lw[2], lw[3]);
}

// ------- split-bf16 GEMM v3: dbuf + global_load_lds + COUNTED vmcnt (T4) ----
// ARM=true : A packed [M][K/8][8], source-swizzled (see k_pack_a)
// ARM=false: A packed [K/8][M][8] (attn-output layout, conflict-free natively)
// B packed [K/8][N][8]. 128x128 tile, BK=32, 4 waves (2x2), 16x16x32 MFMA,
// 3 split terms.  Main loop NEVER drains vmcnt to 0: per step,
//   ds_read(buf) -> lgkmcnt(0) -> barrier -> STAGE(t+2 -> buf) -> MFMA
//   -> vmcnt(8) -> barrier
// keeps 8-16 gl16 loads permanently in flight (stage latency hides under a
// full K-step of compute).  Raw s_barrier: no implicit vmcnt(0) drain.
template<bool ARM>
__global__ __launch_bounds__(256, 2) void k_gemm2(const u16* __restrict__ Ah, const u16* __restrict__ Al,
                                                  const u16* __restrict__ Bh, const u16* __restrict__ Bl,
                                                  const float* __restrict__ bias, float* __restrict__ C,
                                                  int M, int N, int K){
  __shared__ u16 lds[2][4][512][8];   // 64 KiB: [buf][tensor Ah,Al,Bh,Bl][granule][8]
  const int tid = threadIdx.x;
  const int lane = tid & 63, wid = tid >> 6;
  const int q = lane & 15, g = lane >> 4;
  const int m0 = blockIdx.y * 128, n0 = blockIdx.x * 128;   // linear order (T1 reverted)
  const int wr = wid >> 1, wc = wid & 1;
  const int pkK = K >> 3;

  f32x4 acc[4][4];
  #pragma unroll
  for (int a = 0; a < 4; ++a)
    #pragma unroll
    for (int b = 0; b < 4; ++b)
      #pragma unroll
      for (int r = 0; r < 4; ++r) acc[a][b][r] = 0.0f;

  size_t aoff[2], boff[2];
  #pragma unroll
  for (int c = 0; c < 2; ++c){
    int L = c * 256 + tid;
    if (ARM){
      int row = L >> 2, pa = L & 3;
      aoff[c] = ((size_t)(m0 + row) * pkK + pa) * 8;
    } else {
      int pa = L >> 7, row = L & 127;
      aoff[c] = ((size_t)pa * M + m0 + row) * 8;
    }
    int pb = L >> 7, col = L & 127;
    boff[c] = ((size_t)pb * N + n0 + col) * 8;
  }
  const size_t astep = ARM ? (size_t)32 : (size_t)32 * M;   // +4 packets per K-step
  const size_t bstep = (size_t)32 * N;

  const int NT = K >> 5;

  auto STAGE = [&](int b){
    #pragma unroll
    for (int c = 0; c < 2; ++c){
      int lbase = c * 256 + wid * 64;   // wave-uniform LDS granule base
      gl16(Ah + aoff[c], &lds[b][0][lbase][0]);
      gl16(Al + aoff[c], &lds[b][1][lbase][0]);
      gl16(Bh + boff[c], &lds[b][2][lbase][0]);
      gl16(Bl + boff[c], &lds[b][3][lbase][0]);
    }
    aoff[0] += astep; aoff[1] += astep;
    boff[0] += bstep; boff[1] += bstep;
  };

  // prologue: tiles 0 and 1 in flight; drain only tile 0's 8 loads.
  STAGE(0);
  STAGE(1);
  asm volatile("s_waitcnt vmcnt(8)" ::: "memory");
  __builtin_amdgcn_s_barrier();

  int buf = 0;
  for (int t = 0; t < NT; ++t){
    bf16x8 ah[4], al[4], bh[4], bl[4];
    #pragma unroll
    for (int ms = 0; ms < 4; ++ms){
      int row = wr * 64 + ms * 16 + q;
      // ARM=true: read-side XOR matches k_pack_a's source swizzle -> 2-way (free)
      int ia = ARM ? (row * 4 + (g ^ ((row >> 1) & 3))) : (g * 128 + row);
      ah[ms] = *(const bf16x8*)&lds[buf][0][ia][0];
      al[ms] = *(const bf16x8*)&lds[buf][1][ia][0];
    }
    #pragma unroll
    for (int ns = 0; ns < 4; ++ns){
      int col = wc * 64 + ns * 16 + q;
      int ib = g * 128 + col;
      bh[ns] = *(const bf16x8*)&lds[buf][2][ib][0];
      bl[ns] = *(const bf16x8*)&lds[buf][3][ib][0];
    }
    // all of this wave's LDS reads architecturally complete, then block-wide
    // barrier: buf is now free for overwrite by every wave's STAGE.
    asm volatile("s_waitcnt lgkmcnt(0)" ::: "memory");
    __builtin_amdgcn_sched_barrier(0);
    __builtin_amdgcn_s_barrier();
    if (t + 2 < NT) STAGE(buf);          // tile t+2 into the freed buffer

    #pragma unroll
    for (int ms = 0; ms < 4; ++ms)
      #pragma unroll
      for (int ns = 0; ns < 4; ++ns){
        f32x4 tt = acc[ms][ns];
        tt = mfma16(ah[ms], bh[ns], tt);   // hi*hi
        tt = mfma16(ah[ms], bl[ns], tt);   // hi*lo
        tt = mfma16(al[ms], bh[ns], tt);   // lo*hi
        acc[ms][ns] = tt;
      }

    if (t + 2 < NT){
      asm volatile("s_waitcnt vmcnt(8)" ::: "memory");   // drain tile t+1 only
      __builtin_amdgcn_s_barrier();
    } else if (t + 1 < NT){
      asm volatile("s_waitcnt vmcnt(0)" ::: "memory");   // last prefetch drain
      __builtin_amdgcn_s_barrier();
    }
    buf ^= 1;
  }

  #pragma unroll
  for (int ns = 0; ns < 4; ++ns){
    int col = n0 + wc * 64 + ns * 16 + q;
    float bb = bias[col];
    #pragma unroll
    for (int ms = 0; ms < 4; ++ms){
      int row = m0 + wr * 64 + ms * 16 + g * 4;
      #pragma unroll
      for (int r = 0; r < 4; ++r)
        C[(size_t)(row + r) * N + col] = acc[ms][ns][r] + bb;
    }
  }
}

// -------- fused RoPE+scale+split for q AND k: out [h*8][S][8] hi/lo ---------
// grid (S/64, NH+NKV): blockIdx.y < NH -> q head; else k head
__global__ __launch_bounds__(256) void k_rope(const float* __restrict__ qkv,
                                              const float* __restrict__ tab,
                                              u16* __restrict__ qoh, u16* __restrict__ qol,
                                              u16* __restrict__ koh, u16* __restrict__ kol){
  const int sL = threadIdx.x & 63, tp = threadIdx.x >> 6;
  const int s = blockIdx.x * 64 + sL;
  int h = blockIdx.y;
  u16* oh; u16* ol; int srcOff;
  if (h < NH){ oh = qoh; ol = qol; srcOff = h * 64; }
  else       { h -= NH; oh = koh; ol = kol; srcOff = 2048 + h * 64; }
  const float4* src = (const float4*)(qkv + (size_t)s * NQKV + srcOff + tp * 16);
  const float4* tb  = (const float4*)(tab + (size_t)s * 64 + tp * 16);
  float xv[16], tv[16];
  #pragma unroll
  for (int i = 0; i < 4; ++i){
    float4 a = src[i]; float4 b = tb[i];
    xv[4*i+0]=a.x; xv[4*i+1]=a.y; xv[4*i+2]=a.z; xv[4*i+3]=a.w;
    tv[4*i+0]=b.x; tv[4*i+1]=b.y; tv[4*i+2]=b.z; tv[4*i+3]=b.w;
  }
  u32 hw[8], lw[8];
  #pragma unroll
  for (int j = 0; j < 8; ++j){
    float e = xv[2*j], o = xv[2*j+1];
    float c = tv[2*j], sn = tv[2*j+1];
    float f0 = (e * c - o * sn) * SCALE_Q;
    float f1 = (o * c + e * sn) * SCALE_Q;
    split2(f0, f1, hw[j], lw[j]);
  }
  size_t o0 = ((size_t)(h * 8 + tp * 2 + 0) * S_LEN + s) * 8;
  size_t o1 = ((size_t)(h * 8 + tp * 2 + 1) * S_LEN + s) * 8;
  *(uint4*)(oh + o0) = make_uint4(hw[0], hw[1], hw[2], hw[3]);
  *(uint4*)(oh + o1) = make_uint4(hw[4], hw[5], hw[6], hw[7]);
  *(uint4*)(ol + o0) = make_uint4(lw[0], lw[1], lw[2], lw[3]);
  *(uint4*)(ol + o1) = make_uint4(lw[4], lw[5], lw[6], lw[7]);
}

// ---------------- split V transposed: out [NKV][S/8][64][8], LDS-bounced ----
// grid (S/64, NKV)
__global__ __launch_bounds__(256) void k_split_v2(const float* __restrict__ qkv,
                                                  u16* __restrict__ oh, u16* __restrict__ ol){
  __shared__ float tile[64][65];
  const int h = blockIdx.y;
  const int s0 = blockIdx.x * 64;
  {
    const int sL = threadIdx.x >> 2, ch = threadIdx.x & 3;
    const float4* rp = (const float4*)(qkv + (size_t)(s0 + sL) * NQKV + 2560 + h * 64 + ch * 16);
    #pragma unroll
    for (int i = 0; i < 4; ++i){
      float4 w = rp[i];
      tile[sL][ch * 16 + i * 4 + 0] = w.x;
      tile[sL][ch * 16 + i * 4 + 1] = w.y;
      tile[sL][ch * 16 + i * 4 + 2] = w.z;
      tile[sL][ch * 16 + i * 4 + 3] = w.w;
    }
  }
  __syncthreads();
  const int d = threadIdx.x & 63, spg = threadIdx.x >> 6;
  #pragma unroll
  for (int sp2 = 0; sp2 < 2; ++sp2){
    int spl = spg * 2 + sp2;
    float v[8];
    #pragma unroll
    for (int j = 0; j < 8; ++j) v[j] = tile[spl * 8 + j][d];
    u32 hw[4], lw[4];
    #pragma unroll
    for (int j = 0; j < 4; ++j) split2(v[2*j], v[2*j+1], hw[j], lw[j]);
    size_t o_ = (((size_t)h * 256 + blockIdx.x * 8 + spl) * 64 + d) * 8;
    *(uint4*)(oh + o_) = make_uint4(hw[0], hw[1], hw[2], hw[3]);
    *(uint4*)(ol + o_) = make_uint4(lw[0], lw[1], lw[2], lw[3]);
  }
}

// ---------------- banded attention with sink (flash, swapped QK^T) ----------
__global__ __launch_bounds__(256) void k_attn(const u16* __restrict__ qh, const u16* __restrict__ ql,
                                              const u16* __restrict__ kh, const u16* __restrict__ kl,
                                              const u16* __restrict__ vh, const u16* __restrict__ vl,
                                              const float* __restrict__ sinks,
                                              u16* __restrict__ aoh, u16* __restrict__ aol){
  const int lane = threadIdx.x & 63;
  const int wid = threadIdx.x >> 6;
  const int h = blockIdx.x;
  const int hkv = h >> 2;
  const int q0 = blockIdx.y * 128 + wid * 32;
  const int lq = lane & 31;
  const int half = lane >> 5;
  const int qi = q0 + lq;

  bf16x8 qfh[4], qfl[4];
  #pragma unroll
  for (int st = 0; st < 4; ++st){
    size_t off = (((size_t)h * 8 + st * 2 + half) * S_LEN + qi) * 8;
    qfh[st] = *(const bf16x8*)(qh + off);
    qfl[st] = *(const bf16x8*)(ql + off);
  }
  float m = sinks[h];
  float lsum = 1.0f;
  f32x16 o0, o1;
  #pragma unroll
  for (int r = 0; r < 16; ++r){ o0[r] = 0.0f; o1[r] = 0.0f; }

  const int kb0 = q0 - 128;
  for (int c = 0; c < 9; ++c){
    const int kb = kb0 + c * 32;
    if (kb + 32 <= 0 || kb >= S_LEN) continue;
    const int keyr = kb + lq;
    const int keyc = min(max(keyr, 0), S_LEN - 1);
    f32x16 sc;
    #pragma unroll
    for (int r = 0; r < 16; ++r) sc[r] = 0.0f;
    #pragma unroll
    for (int st = 0; st < 4; ++st){
      size_t ko = (((size_t)hkv * 8 + st * 2 + half) * S_LEN + keyc) * 8;
      bf16x8 kfh = *(const bf16x8*)(kh + ko);
      bf16x8 kfl = *(const bf16x8*)(kl + ko);
      sc = mfma32(kfh, qfh[st], sc);
      sc = mfma32(kfh, qfl[st], sc);
      sc = mfma32(kfl, qfh[st], sc);
    }
    float tmax = -3.0e38f;
    #pragma unroll
    for (int r = 0; r < 16; ++r){
      int key = kb + (r & 3) + 8 * (r >> 2) + 4 * half;
      int dd = qi - key; if (dd < 0) dd = -dd;
      bool ok = (key >= 0) && (key < S_LEN) && (dd <= SWIN);
      sc[r] = ok ? sc[r] : NEGV;
      tmax = fmaxf(tmax, sc[r]);
    }
    tmax = fmaxf(tmax, __shfl_xor(tmax, 32));
    float mn = fmaxf(m, tmax);
    float alpha = __expf(m - mn);
    m = mn;
    float p[16]; float ps = 0.0f;
    #pragma unroll
    for (int r = 0; r < 16; ++r){ p[r] = __expf(sc[r] - mn); ps += p[r]; }
    ps += __shfl_xor(ps, 32);
    lsum = lsum * alpha + ps;
    #pragma unroll
    for (int r = 0; r < 16; ++r){ o0[r] *= alpha; o1[r] *= alpha; }
    u32 wh[8], wl[8];
    #pragma unroll
    for (int j = 0; j < 8; ++j) split2(p[2 * j], p[2 * j + 1], wh[j], wl[j]);
    bf16x8 pfh[2], pfl[2];
    #pragma unroll
    for (int ks = 0; ks < 2; ++ks){
      u32 x0 = wh[4 * ks + 0], y0 = wh[4 * ks + 2];
      u32 x1 = wh[4 * ks + 1], y1 = wh[4 * ks + 3];
      u32 sx0 = __shfl_xor(x0, 32), sy0 = __shfl_xor(y0, 32);
      u32 sx1 = __shfl_xor(x1, 32), sy1 = __shfl_xor(y1, 32);
      union { u32 u[4]; bf16x8 b; } fb;
      fb.u[0] = half ? sy0 : x0;
      fb.u[1] = half ? sy1 : x1;
      fb.u[2] = half ? y0 : sx0;
      fb.u[3] = half ? y1 : sx1;
      pfh[ks] = fb.b;
      u32 a0 = wl[4 * ks + 0], b0 = wl[4 * ks + 2];
      u32 a1 = wl[4 * ks + 1], b1 = wl[4 * ks + 3];
      u32 sa0 = __shfl_xor(a0, 32), sb0 = __shfl_xor(b0, 32);
      u32 sa1 = __shfl_xor(a1, 32), sb1 = __shfl_xor(b1, 32);
      fb.u[0] = half ? sb0 : a0;
      fb.u[1] = half ? sb1 : a1;
      fb.u[2] = half ? b0 : sa0;
      fb.u[3] = half ? b1 : sa1;
      pfl[ks] = fb.b;
    }
    #pragma unroll
    for (int ks = 0; ks < 2; ++ks){
      int kp = kb / 8 + ks * 2 + half;
      kp = min(max(kp, 0), S_LEN / 8 - 1);
      #pragma unroll
      for (int nt = 0; nt < 2; ++nt){
        size_t vo = (((size_t)hkv * 256 + kp) * 64 + nt * 32 + lq) * 8;
        bf16x8 vfh = *(const bf16x8*)(vh + vo);
        bf16x8 vfl = *(const bf16x8*)(vl + vo);
        f32x16 acc = (nt == 0) ? o0 : o1;
        acc = mfma32(vfh, pfh[ks], acc);
        acc = mfma32(vfh, pfl[ks], acc);
        acc = mfma32(vfl, pfh[ks], acc);
        if (nt == 0) o0 = acc; else o1 = acc;
      }
    }
  }
  float inv = 1.0f / lsum;
  #pragma unroll
  for (int nt = 0; nt < 2; ++nt){
    f32x16 o = (nt == 0) ? o0 : o1;
    #pragma unroll
    for (int rr = 0; rr < 4; ++rr){
      int d0 = nt * 32 + 8 * rr + 4 * half;
      u32 hw0, hw1, lw0, lw1;
      float v0 = o[rr * 4 + 0] * inv, v1 = o[rr * 4 + 1] * inv;
      float v2 = o[rr * 4 + 2] * inv, v3 = o[rr * 4 + 3] * inv;
      split2(v0, v1, hw0, lw0);
      split2(v2, v3, hw1, lw1);
      int kp_ = h * 8 + nt * 4 + rr;
      size_t oo = ((size_t)kp_ * S_LEN + qi) * 8 + (d0 & 7);
      uint2 wv; wv.x = hw0; wv.y = hw1;
      *(uint2*)(aoh + oo) = wv;
      wv.x = lw0; wv.y = lw1;
      *(uint2*)(aol + oo) = wv;
    }
  }
}

// ---------------------------------------------------------------------------
extern "C" void kernel_launch(void* const* d_in, const int* in_sizes, int n_in,
                              void* d_out, int out_size, void* d_ws, size_t ws_size,
                              hipStream_t stream){
  const float* hid = (const float*)d_in[0];
  const float* Wq  = (const float*)d_in[1];
  const float* bq  = (const float*)d_in[2];
  const float* Wk  = (const float*)d_in[3];
  const float* bk  = (const float*)d_in[4];
  const float* Wv  = (const float*)d_in[5];
  const float* bv  = (const float*)d_in[6];
  const float* Wo  = (const float*)d_in[7];
  const float* bo  = (const float*)d_in[8];
  const float* sinks = (const float*)d_in[9];
  float* out = (float*)d_out;

  char* w = (char*)d_ws;
  size_t off = 0;
  auto alloc = [&](size_t bytes){ void* p = w + off; off += (bytes + 255) & ~(size_t)255; return p; };
  float* ropetab = (float*)alloc((size_t)S_LEN * 32 * 2 * 4);
  float* bias3   = (float*)alloc((size_t)NQKV * 4);
  u16* Ah  = (u16*)alloc((size_t)2048 * 2048 * 2);        // hidden packed [M][K/8][8] swz
  u16* Al  = (u16*)alloc((size_t)2048 * 2048 * 2);
  u16* Bh  = (u16*)alloc((size_t)256 * NQKV * 8 * 2);     // Wq|Wk|Wv packed [K/8][N][8]
  u16* Bl  = (u16*)alloc((size_t)256 * NQKV * 8 * 2);
  float* QKV = (float*)alloc((size_t)S_LEN * NQKV * 4);
  u16* qph = (u16*)alloc((size_t)NH * 8 * S_LEN * 8 * 2);
  u16* qpl = (u16*)alloc((size_t)NH * 8 * S_LEN * 8 * 2);
  u16* kph = (u16*)alloc((size_t)NKV * 8 * S_LEN * 8 * 2);
  u16* kpl = (u16*)alloc((size_t)NKV * 8 * S_LEN * 8 * 2);
  u16* vph = (u16*)alloc((size_t)NKV * 256 * 64 * 8 * 2);
  u16* vpl = (u16*)alloc((size_t)NKV * 256 * 64 * 8 * 2);
  u16* aoh = (u16*)alloc((size_t)256 * S_LEN * 8 * 2);    // attn out [K/8][S][8]
  u16* aol = (u16*)alloc((size_t)256 * S_LEN * 8 * 2);
  u16* Woh = (u16*)alloc((size_t)256 * 2048 * 8 * 2);
  u16* Wol = (u16*)alloc((size_t)256 * 2048 * 8 * 2);
  (void)in_sizes; (void)n_in; (void)out_size; (void)ws_size;

  k_prep<<<256, 256, 0, stream>>>(bq, bk, bv, ropetab, bias3);
  k_pack_a<<<2048, 256, 0, stream>>>(hid, Ah, Al, 2048 * 256);
  k_pack_w<<<2048, 256, 0, stream>>>(Wq, Bh, Bl, 2048, 2048, NQKV, 0);
  k_pack_w<<<512, 256, 0, stream>>>(Wk, Bh, Bl, 2048, 512, NQKV, 2048);
  k_pack_w<<<512, 256, 0, stream>>>(Wv, Bh, Bl, 2048, 512, NQKV, 2560);
  k_pack_w<<<2048, 256, 0, stream>>>(Wo, Woh, Wol, 2048, 2048, 2048, 0);
  k_gemm2<true><<<dim3(NQKV / 128, 2048 / 128), 256, 0, stream>>>(Ah, Al, Bh, Bl, bias3, QKV,
                                                                  2048, NQKV, 2048);
  k_rope<<<dim3(32, NH + NKV), 256, 0, stream>>>(QKV, ropetab, qph, qpl, kph, kpl);
  k_split_v2<<<dim3(32, NKV), 256, 0, stream>>>(QKV, vph, vpl);
  k_attn<<<dim3(NH, S_LEN / 128), 256, 0, stream>>>(qph, qpl, kph, kpl, vph, vpl, sinks, aoh, aol);
  k_gemm2<false><<<dim3(2048 / 128, 2048 / 128), 256, 0, stream>>>(aoh, aol, Woh, Wol, bo, out,
                                                                   2048, 2048, 2048);
}

// Round 7
// 293.473 us; speedup vs baseline: 1.0276x; 1.0276x over previous
//
#include <hip/hip_runtime.h>
#include <hip/hip_bf16.h>
#include <stdint.h>

typedef unsigned short u16;
typedef unsigned int   u32;

#define S_LEN 2048
#define NQKV  3072
#define NH    32
#define NKV   8
#define SWIN  128
#define NEGV  (-1.0e9f)
#define SCALE_Q 0.35355339059327379f   // 64^-0.25

typedef __attribute__((ext_vector_type(4)))  float  f32x4;
typedef __attribute__((ext_vector_type(16))) float  f32x16;
typedef __attribute__((ext_vector_type(8)))  __bf16 bf16x8;

__device__ __forceinline__ u16 f2bf(float x){
  u32 u = __float_as_uint(x);
  return (u16)((u + 0x7fffu + ((u >> 16) & 1u)) >> 16);   // RNE
}
__device__ __forceinline__ float bf2f(u16 h){
  return __uint_as_float(((u32)h) << 16);
}
__device__ __forceinline__ void split2(float a, float b, u32& hw, u32& lw){
  u16 ha = f2bf(a), hb = f2bf(b);
  u16 la = f2bf(a - bf2f(ha)), lb = f2bf(b - bf2f(hb));
  hw = (u32)ha | ((u32)hb << 16);
  lw = (u32)la | ((u32)lb << 16);
}
__device__ __forceinline__ f32x4 mfma16(bf16x8 a, bf16x8 b, f32x4 c){
  return __builtin_amdgcn_mfma_f32_16x16x32_bf16(a, b, c, 0, 0, 0);
}
__device__ __forceinline__ f32x16 mfma32(bf16x8 a, bf16x8 b, f32x16 c){
  return __builtin_amdgcn_mfma_f32_32x32x16_bf16(a, b, c, 0, 0, 0);
}

typedef __attribute__((address_space(1))) const unsigned int ga_u32;
typedef __attribute__((address_space(3))) unsigned int       ls_u32;
__device__ __forceinline__ void gl16(const void* g, void* l){
  // direct global->LDS, 16B per lane; LDS dest = wave-uniform base + lane*16
  __builtin_amdgcn_global_load_lds((ga_u32*)g, (ls_u32*)l, 16, 0, 0);
}

// ---------------- prep: rope table [S][32][(cos,sin)] + packed bias[3072] ----
__global__ __launch_bounds__(256) void k_prep(const float* __restrict__ bq,
                                              const float* __restrict__ bk,
                                              const float* __restrict__ bv,
                                              float* __restrict__ ropetab,
                                              float* __restrict__ bias3){
  int id = blockIdx.x * 256 + threadIdx.x;        // S*32 threads
  int t = id >> 5, i = id & 31;
  float e = (i * 2.0f) / 64.0f;
  float base = (float)pow(150000.0, (double)e);
  float invf = 1.0f / base;
  float fr = (float)t * invf;
  ropetab[(size_t)id * 2 + 0] = cosf(fr);
  ropetab[(size_t)id * 2 + 1] = sinf(fr);
  if (id < NQKV){
    float b;
    if (id < 2048) b = bq[id];
    else if (id < 2560) b = bk[id - 2048];
    else b = bv[id - 2560];
    bias3[id] = b;
  }
}

// ---- pack A streaming: fp32 row-major -> hi/lo bf16 [M][K/8][8], SWIZZLED ---
// granule (r,p) stored at p' = (p&~3) | ((p&3) ^ ((r>>1)&3)).  Bijective within
// each aligned 4-packet group (same 64B line -> coalescing preserved).  The
// GEMM's LDS read applies the same XOR -> conflict-free ds_read_b128.
__global__ __launch_bounds__(256) void k_pack_a(const float* __restrict__ in,
                                                u16* __restrict__ oh, u16* __restrict__ ol,
                                                int n8){
  int id = blockIdx.x * 256 + threadIdx.x;
  if (id >= n8) return;
  int r = id >> 8, p = id & 255;              // P = 256 packets per row
  const float4* src = (const float4*)(in + (size_t)id * 8);
  float4 v0 = src[0], v1 = src[1];
  u32 hw[4], lw[4];
  split2(v0.x, v0.y, hw[0], lw[0]);
  split2(v0.z, v0.w, hw[1], lw[1]);
  split2(v1.x, v1.y, hw[2], lw[2]);
  split2(v1.z, v1.w, hw[3], lw[3]);
  int psw = (p & ~3) | ((p & 3) ^ ((r >> 1) & 3));
  size_t o = ((size_t)r * 256 + psw) * 8;
  *(uint4*)(oh + o) = make_uint4(hw[0], hw[1], hw[2], hw[3]);
  *(uint4*)(ol + o) = make_uint4(lw[0], lw[1], lw[2], lw[3]);
}

// ---------------- pack W: fp32 [K][N] (N contig) -> [K/8][NTot][8] at nOff ---
__global__ __launch_bounds__(256) void k_pack_w(const float* __restrict__ w,
                                                u16* __restrict__ oh, u16* __restrict__ ol,
                                                int K, int N, int NTot, int nOff){
  int id = blockIdx.x * 256 + threadIdx.x;
  int P = K >> 3;
  if (id >= P * N) return;
  int p = id / N, n = id % N;
  u32 hw[4], lw[4];
  #pragma unroll
  for (int j = 0; j < 4; ++j){
    float a = w[(size_t)(8 * p + 2 * j) * N + n];
    float b = w[(size_t)(8 * p + 2 * j + 1) * N + n];
    split2(a, b, hw[j], lw[j]);
  }
  size_t o = ((size_t)p * NTot + nOff + n) * 8;
  *(uint4*)(oh + o) = make_uint4(hw[0], hw[1], hw[2], hw[3]);
  *(uint4*)(ol + o) = make_uint4(lw[0], lw[1], lw[2], lw[3]);
}

// -- split-bf16 GEMM v4: reg-dbuf pipeline, LDS-read(t+1) overlaps MFMA(t) ---
// ARM=true : A packed [M][K/8][8], source-swizzled (see k_pack_a)
// ARM=false: A packed [K/8][M][8] (attn-output layout, conflict-free natively)
// B packed [K/8][N][8]. 128x128 tile, BK=32, 4 waves (2x2), 16x16x32 MFMA,
// 3 split terms.  Per phase: STAGE(t+2) -> vmcnt(8) -> barrier(data ready) ->
// {ds_read frag(t+1) || MFMA frag(t)} -> lgkmcnt(0) -> barrier(buf free).
// Loop unrolled x2 with named frag sets (no runtime-indexed reg arrays).
template<bool ARM>
__global__ __launch_bounds__(256, 2) void k_gemm2(const u16* __restrict__ Ah, const u16* __restrict__ Al,
                                                  const u16* __restrict__ Bh, const u16* __restrict__ Bl,
                                                  const float* __restrict__ bias, float* __restrict__ C,
                                                  int M, int N, int K){
  __shared__ u16 lds[2][4][512][8];   // 64 KiB: [buf][tensor Ah,Al,Bh,Bl][granule][8]
  const int tid = threadIdx.x;
  const int lane = tid & 63, wid = tid >> 6;
  const int q = lane & 15, g = lane >> 4;
  const int m0 = blockIdx.y * 128, n0 = blockIdx.x * 128;
  const int wr = wid >> 1, wc = wid & 1;
  const int pkK = K >> 3;

  f32x4 acc[4][4];
  #pragma unroll
  for (int a = 0; a < 4; ++a)
    #pragma unroll
    for (int b = 0; b < 4; ++b)
      #pragma unroll
      for (int r = 0; r < 4; ++r) acc[a][b][r] = 0.0f;

  size_t aoff[2], boff[2];
  #pragma unroll
  for (int c = 0; c < 2; ++c){
    int L = c * 256 + tid;
    if (ARM){
      int row = L >> 2, pa = L & 3;
      aoff[c] = ((size_t)(m0 + row) * pkK + pa) * 8;
    } else {
      int pa = L >> 7, row = L & 127;
      aoff[c] = ((size_t)pa * M + m0 + row) * 8;
    }
    int pb = L >> 7, col = L & 127;
    boff[c] = ((size_t)pb * N + n0 + col) * 8;
  }
  const size_t astep = ARM ? (size_t)32 : (size_t)32 * M;   // +4 packets per K-step
  const size_t bstep = (size_t)32 * N;

  const int NT = K >> 5;   // even, >= 4

  auto STAGE = [&](int b){
    #pragma unroll
    for (int c = 0; c < 2; ++c){
      int lbase = c * 256 + wid * 64;   // wave-uniform LDS granule base
      gl16(Ah + aoff[c], &lds[b][0][lbase][0]);
      gl16(Al + aoff[c], &lds[b][1][lbase][0]);
      gl16(Bh + boff[c], &lds[b][2][lbase][0]);
      gl16(Bl + boff[c], &lds[b][3][lbase][0]);
    }
    aoff[0] += astep; aoff[1] += astep;
    boff[0] += bstep; boff[1] += bstep;
  };

  // per-fragment LDS granule indices (compile-time after unroll)
  int iaIdx[4], ibIdx[4];
  #pragma unroll
  for (int ms = 0; ms < 4; ++ms){
    int row = wr * 64 + ms * 16 + q;
    iaIdx[ms] = ARM ? (row * 4 + (g ^ ((row >> 1) & 3))) : (g * 128 + row);
    int col = wc * 64 + ms * 16 + q;
    ibIdx[ms] = g * 128 + col;
  }

  bf16x8 a0h[4], a0l[4], b0h[4], b0l[4];   // frag set 0 (even tiles)
  bf16x8 a1h[4], a1l[4], b1h[4], b1l[4];   // frag set 1 (odd tiles)

#define LF(AH,AL,BH,BL,BUF) do{ \
    _Pragma("unroll") \
    for (int ms = 0; ms < 4; ++ms){ \
      AH[ms] = *(const bf16x8*)&lds[BUF][0][iaIdx[ms]][0]; \
      AL[ms] = *(const bf16x8*)&lds[BUF][1][iaIdx[ms]][0]; \
      BH[ms] = *(const bf16x8*)&lds[BUF][2][ibIdx[ms]][0]; \
      BL[ms] = *(const bf16x8*)&lds[BUF][3][ibIdx[ms]][0]; \
    } }while(0)

#define MM(AH,AL,BH,BL) do{ \
    _Pragma("unroll") \
    for (int ms = 0; ms < 4; ++ms) \
      _Pragma("unroll") \
      for (int ns = 0; ns < 4; ++ns){ \
        f32x4 tt = acc[ms][ns]; \
        tt = mfma16(AH[ms], BH[ns], tt); \
        tt = mfma16(AH[ms], BL[ns], tt); \
        tt = mfma16(AL[ms], BH[ns], tt); \
        acc[ms][ns] = tt; \
      } }while(0)

  // prologue: tiles 0,1 in flight; read frag(0) once tile0 lands.
  STAGE(0);
  STAGE(1);
  asm volatile("s_waitcnt vmcnt(8)" ::: "memory");
  __builtin_amdgcn_s_barrier();
  LF(a0h, a0l, b0h, b0l, 0);
  asm volatile("s_waitcnt lgkmcnt(0)" ::: "memory");
  __builtin_amdgcn_sched_barrier(0);
  __builtin_amdgcn_s_barrier();          // buf0 free for overwrite

  for (int t = 0; t < NT; t += 2){
    // ---- phase A: MFMA tile t (set0) || ds_read tile t+1 (buf1 -> set1) ----
    if (t + 2 < NT) STAGE(0);            // tile t+2 -> buf0 (freed above)
    if (t + 2 < NT) asm volatile("s_waitcnt vmcnt(8)" ::: "memory");
    else            asm volatile("s_waitcnt vmcnt(0)" ::: "memory");
    __builtin_amdgcn_s_barrier();        // tile t+1 ready in buf1 (all waves)
    LF(a1h, a1l, b1h, b1l, 1);
    MM(a0h, a0l, b0h, b0l);
    asm volatile("s_waitcnt lgkmcnt(0)" ::: "memory");
    __builtin_amdgcn_sched_barrier(0);
    __builtin_amdgcn_s_barrier();        // buf1 free for overwrite
    // ---- phase B: MFMA tile t+1 (set1) || ds_read tile t+2 (buf0 -> set0) --
    if (t + 3 < NT) STAGE(1);            // tile t+3 -> buf1
    if (t + 3 < NT) asm volatile("s_waitcnt vmcnt(8)" ::: "memory");
    else            asm volatile("s_waitcnt vmcnt(0)" ::: "memory");
    __builtin_amdgcn_s_barrier();        // tile t+2 ready in buf0
    if (t + 2 < NT) LF(a0h, a0l, b0h, b0l, 0);
    MM(a1h, a1l, b1h, b1l);
    asm volatile("s_waitcnt lgkmcnt(0)" ::: "memory");
    __builtin_amdgcn_sched_barrier(0);
    __builtin_amdgcn_s_barrier();        // buf0 free for overwrite
  }
#undef LF
#undef MM

  #pragma unroll
  for (int ns = 0; ns < 4; ++ns){
    int col = n0 + wc * 64 + ns * 16 + q;
    float bb = bias[col];
    #pragma unroll
    for (int ms = 0; ms < 4; ++ms){
      int row = m0 + wr * 64 + ms * 16 + g * 4;
      #pragma unroll
      for (int r = 0; r < 4; ++r)
        C[(size_t)(row + r) * N + col] = acc[ms][ns][r] + bb;
    }
  }
}

// -------- fused RoPE+scale+split for q AND k: out [h*8][S][8] hi/lo ---------
// grid (S/64, NH+NKV): blockIdx.y < NH -> q head; else k head
__global__ __launch_bounds__(256) void k_rope(const float* __restrict__ qkv,
                                              const float* __restrict__ tab,
                                              u16* __restrict__ qoh, u16* __restrict__ qol,
                                              u16* __restrict__ koh, u16* __restrict__ kol){
  const int sL = threadIdx.x & 63, tp = threadIdx.x >> 6;
  const int s = blockIdx.x * 64 + sL;
  int h = blockIdx.y;
  u16* oh; u16* ol; int srcOff;
  if (h < NH){ oh = qoh; ol = qol; srcOff = h * 64; }
  else       { h -= NH; oh = koh; ol = kol; srcOff = 2048 + h * 64; }
  const float4* src = (const float4*)(qkv + (size_t)s * NQKV + srcOff + tp * 16);
  const float4* tb  = (const float4*)(tab + (size_t)s * 64 + tp * 16);
  float xv[16], tv[16];
  #pragma unroll
  for (int i = 0; i < 4; ++i){
    float4 a = src[i]; float4 b = tb[i];
    xv[4*i+0]=a.x; xv[4*i+1]=a.y; xv[4*i+2]=a.z; xv[4*i+3]=a.w;
    tv[4*i+0]=b.x; tv[4*i+1]=b.y; tv[4*i+2]=b.z; tv[4*i+3]=b.w;
  }
  u32 hw[8], lw[8];
  #pragma unroll
  for (int j = 0; j < 8; ++j){
    float e = xv[2*j], o = xv[2*j+1];
    float c = tv[2*j], sn = tv[2*j+1];
    float f0 = (e * c - o * sn) * SCALE_Q;
    float f1 = (o * c + e * sn) * SCALE_Q;
    split2(f0, f1, hw[j], lw[j]);
  }
  size_t o0 = ((size_t)(h * 8 + tp * 2 + 0) * S_LEN + s) * 8;
  size_t o1 = ((size_t)(h * 8 + tp * 2 + 1) * S_LEN + s) * 8;
  *(uint4*)(oh + o0) = make_uint4(hw[0], hw[1], hw[2], hw[3]);
  *(uint4*)(oh + o1) = make_uint4(hw[4], hw[5], hw[6], hw[7]);
  *(uint4*)(ol + o0) = make_uint4(lw[0], lw[1], lw[2], lw[3]);
  *(uint4*)(ol + o1) = make_uint4(lw[4], lw[5], lw[6], lw[7]);
}

// ---------------- split V transposed: out [NKV][S/8][64][8], LDS-bounced ----
// grid (S/64, NKV)
__global__ __launch_bounds__(256) void k_split_v2(const float* __restrict__ qkv,
                                                  u16* __restrict__ oh, u16* __restrict__ ol){
  __shared__ float tile[64][65];
  const int h = blockIdx.y;
  const int s0 = blockIdx.x * 64;
  {
    const int sL = threadIdx.x >> 2, ch = threadIdx.x & 3;
    const float4* rp = (const float4*)(qkv + (size_t)(s0 + sL) * NQKV + 2560 + h * 64 + ch * 16);
    #pragma unroll
    for (int i = 0; i < 4; ++i){
      float4 w = rp[i];
      tile[sL][ch * 16 + i * 4 + 0] = w.x;
      tile[sL][ch * 16 + i * 4 + 1] = w.y;
      tile[sL][ch * 16 + i * 4 + 2] = w.z;
      tile[sL][ch * 16 + i * 4 + 3] = w.w;
    }
  }
  __syncthreads();
  const int d = threadIdx.x & 63, spg = threadIdx.x >> 6;
  #pragma unroll
  for (int sp2 = 0; sp2 < 2; ++sp2){
    int spl = spg * 2 + sp2;
    float v[8];
    #pragma unroll
    for (int j = 0; j < 8; ++j) v[j] = tile[spl * 8 + j][d];
    u32 hw[4], lw[4];
    #pragma unroll
    for (int j = 0; j < 4; ++j) split2(v[2*j], v[2*j+1], hw[j], lw[j]);
    size_t o_ = (((size_t)h * 256 + blockIdx.x * 8 + spl) * 64 + d) * 8;
    *(uint4*)(oh + o_) = make_uint4(hw[0], hw[1], hw[2], hw[3]);
    *(uint4*)(ol + o_) = make_uint4(lw[0], lw[1], lw[2], lw[3]);
  }
}

// ---------------- banded attention with sink (flash, swapped QK^T) ----------
__global__ __launch_bounds__(256) void k_attn(const u16* __restrict__ qh, const u16* __restrict__ ql,
                                              const u16* __restrict__ kh, const u16* __restrict__ kl,
                                              const u16* __restrict__ vh, const u16* __restrict__ vl,
                                              const float* __restrict__ sinks,
                                              u16* __restrict__ aoh, u16* __restrict__ aol){
  const int lane = threadIdx.x & 63;
  const int wid = threadIdx.x >> 6;
  const int h = blockIdx.x;
  const int hkv = h >> 2;
  const int q0 = blockIdx.y * 128 + wid * 32;
  const int lq = lane & 31;
  const int half = lane >> 5;
  const int qi = q0 + lq;

  bf16x8 qfh[4], qfl[4];
  #pragma unroll
  for (int st = 0; st < 4; ++st){
    size_t off = (((size_t)h * 8 + st * 2 + half) * S_LEN + qi) * 8;
    qfh[st] = *(const bf16x8*)(qh + off);
    qfl[st] = *(const bf16x8*)(ql + off);
  }
  float m = sinks[h];
  float lsum = 1.0f;
  f32x16 o0, o1;
  #pragma unroll
  for (int r = 0; r < 16; ++r){ o0[r] = 0.0f; o1[r] = 0.0f; }

  const int kb0 = q0 - 128;
  for (int c = 0; c < 9; ++c){
    const int kb = kb0 + c * 32;
    if (kb + 32 <= 0 || kb >= S_LEN) continue;
    const int keyr = kb + lq;
    const int keyc = min(max(keyr, 0), S_LEN - 1);
    f32x16 sc;
    #pragma unroll
    for (int r = 0; r < 16; ++r) sc[r] = 0.0f;
    #pragma unroll
    for (int st = 0; st < 4; ++st){
      size_t ko = (((size_t)hkv * 8 + st * 2 + half) * S_LEN + keyc) * 8;
      bf16x8 kfh = *(const bf16x8*)(kh + ko);
      bf16x8 kfl = *(const bf16x8*)(kl + ko);
      sc = mfma32(kfh, qfh[st], sc);
      sc = mfma32(kfh, qfl[st], sc);
      sc = mfma32(kfl, qfh[st], sc);
    }
    float tmax = -3.0e38f;
    #pragma unroll
    for (int r = 0; r < 16; ++r){
      int key = kb + (r & 3) + 8 * (r >> 2) + 4 * half;
      int dd = qi - key; if (dd < 0) dd = -dd;
      bool ok = (key >= 0) && (key < S_LEN) && (dd <= SWIN);
      sc[r] = ok ? sc[r] : NEGV;
      tmax = fmaxf(tmax, sc[r]);
    }
    tmax = fmaxf(tmax, __shfl_xor(tmax, 32));
    float mn = fmaxf(m, tmax);
    float alpha = __expf(m - mn);
    m = mn;
    float p[16]; float ps = 0.0f;
    #pragma unroll
    for (int r = 0; r < 16; ++r){ p[r] = __expf(sc[r] - mn); ps += p[r]; }
    ps += __shfl_xor(ps, 32);
    lsum = lsum * alpha + ps;
    #pragma unroll
    for (int r = 0; r < 16; ++r){ o0[r] *= alpha; o1[r] *= alpha; }
    u32 wh[8], wl[8];
    #pragma unroll
    for (int j = 0; j < 8; ++j) split2(p[2 * j], p[2 * j + 1], wh[j], wl[j]);
    bf16x8 pfh[2], pfl[2];
    #pragma unroll
    for (int ks = 0; ks < 2; ++ks){
      u32 x0 = wh[4 * ks + 0], y0 = wh[4 * ks + 2];
      u32 x1 = wh[4 * ks + 1], y1 = wh[4 * ks + 3];
      u32 sx0 = __shfl_xor(x0, 32), sy0 = __shfl_xor(y0, 32);
      u32 sx1 = __shfl_xor(x1, 32), sy1 = __shfl_xor(y1, 32);
      union { u32 u[4]; bf16x8 b; } fb;
      fb.u[0] = half ? sy0 : x0;
      fb.u[1] = half ? sy1 : x1;
      fb.u[2] = half ? y0 : sx0;
      fb.u[3] = half ? y1 : sx1;
      pfh[ks] = fb.b;
      u32 a0 = wl[4 * ks + 0], b0 = wl[4 * ks + 2];
      u32 a1 = wl[4 * ks + 1], b1 = wl[4 * ks + 3];
      u32 sa0 = __shfl_xor(a0, 32), sb0 = __shfl_xor(b0, 32);
      u32 sa1 = __shfl_xor(a1, 32), sb1 = __shfl_xor(b1, 32);
      fb.u[0] = half ? sb0 : a0;
      fb.u[1] = half ? sb1 : a1;
      fb.u[2] = half ? b0 : sa0;
      fb.u[3] = half ? b1 : sa1;
      pfl[ks] = fb.b;
    }
    #pragma unroll
    for (int ks = 0; ks < 2; ++ks){
      int kp = kb / 8 + ks * 2 + half;
      kp = min(max(kp, 0), S_LEN / 8 - 1);
      #pragma unroll
      for (int nt = 0; nt < 2; ++nt){
        size_t vo = (((size_t)hkv * 256 + kp) * 64 + nt * 32 + lq) * 8;
        bf16x8 vfh = *(const bf16x8*)(vh + vo);
        bf16x8 vfl = *(const bf16x8*)(vl + vo);
        f32x16 acc = (nt == 0) ? o0 : o1;
        acc = mfma32(vfh, pfh[ks], acc);
        acc = mfma32(vfh, pfl[ks], acc);
        acc = mfma32(vfl, pfh[ks], acc);
        if (nt == 0) o0 = acc; else o1 = acc;
      }
    }
  }
  float inv = 1.0f / lsum;
  #pragma unroll
  for (int nt = 0; nt < 2; ++nt){
    f32x16 o = (nt == 0) ? o0 : o1;
    #pragma unroll
    for (int rr = 0; rr < 4; ++rr){
      int d0 = nt * 32 + 8 * rr + 4 * half;
      u32 hw0, hw1, lw0, lw1;
      float v0 = o[rr * 4 + 0] * inv, v1 = o[rr * 4 + 1] * inv;
      float v2 = o[rr * 4 + 2] * inv, v3 = o[rr * 4 + 3] * inv;
      split2(v0, v1, hw0, lw0);
      split2(v2, v3, hw1, lw1);
      int kp_ = h * 8 + nt * 4 + rr;
      size_t oo = ((size_t)kp_ * S_LEN + qi) * 8 + (d0 & 7);
      uint2 wv; wv.x = hw0; wv.y = hw1;
      *(uint2*)(aoh + oo) = wv;
      wv.x = lw0; wv.y = lw1;
      *(uint2*)(aol + oo) = wv;
    }
  }
}

// ---------------------------------------------------------------------------
extern "C" void kernel_launch(void* const* d_in, const int* in_sizes, int n_in,
                              void* d_out, int out_size, void* d_ws, size_t ws_size,
                              hipStream_t stream){
  const float* hid = (const float*)d_in[0];
  const float* Wq  = (const float*)d_in[1];
  const float* bq  = (const float*)d_in[2];
  const float* Wk  = (const float*)d_in[3];
  const float* bk  = (const float*)d_in[4];
  const float* Wv  = (const float*)d_in[5];
  const float* bv  = (const float*)d_in[6];
  const float* Wo  = (const float*)d_in[7];
  const float* bo  = (const float*)d_in[8];
  const float* sinks = (const float*)d_in[9];
  float* out = (float*)d_out;

  char* w = (char*)d_ws;
  size_t off = 0;
  auto alloc = [&](size_t bytes){ void* p = w + off; off += (bytes + 255) & ~(size_t)255; return p; };
  float* ropetab = (float*)alloc((size_t)S_LEN * 32 * 2 * 4);
  float* bias3   = (float*)alloc((size_t)NQKV * 4);
  u16* Ah  = (u16*)alloc((size_t)2048 * 2048 * 2);        // hidden packed [M][K/8][8] swz
  u16* Al  = (u16*)alloc((size_t)2048 * 2048 * 2);
  u16* Bh  = (u16*)alloc((size_t)256 * NQKV * 8 * 2);     // Wq|Wk|Wv packed [K/8][N][8]
  u16* Bl  = (u16*)alloc((size_t)256 * NQKV * 8 * 2);
  float* QKV = (float*)alloc((size_t)S_LEN * NQKV * 4);
  u16* qph = (u16*)alloc((size_t)NH * 8 * S_LEN * 8 * 2);
  u16* qpl = (u16*)alloc((size_t)NH * 8 * S_LEN * 8 * 2);
  u16* kph = (u16*)alloc((size_t)NKV * 8 * S_LEN * 8 * 2);
  u16* kpl = (u16*)alloc((size_t)NKV * 8 * S_LEN * 8 * 2);
  u16* vph = (u16*)alloc((size_t)NKV * 256 * 64 * 8 * 2);
  u16* vpl = (u16*)alloc((size_t)NKV * 256 * 64 * 8 * 2);
  u16* aoh = (u16*)alloc((size_t)256 * S_LEN * 8 * 2);    // attn out [K/8][S][8]
  u16* aol = (u16*)alloc((size_t)256 * S_LEN * 8 * 2);
  u16* Woh = (u16*)alloc((size_t)256 * 2048 * 8 * 2);
  u16* Wol = (u16*)alloc((size_t)256 * 2048 * 8 * 2);
  (void)in_sizes; (void)n_in; (void)out_size; (void)ws_size;

  k_prep<<<256, 256, 0, stream>>>(bq, bk, bv, ropetab, bias3);
  k_pack_a<<<2048, 256, 0, stream>>>(hid, Ah, Al, 2048 * 256);
  k_pack_w<<<2048, 256, 0, stream>>>(Wq, Bh, Bl, 2048, 2048, NQKV, 0);
  k_pack_w<<<512, 256, 0, stream>>>(Wk, Bh, Bl, 2048, 512, NQKV, 2048);
  k_pack_w<<<512, 256, 0, stream>>>(Wv, Bh, Bl, 2048, 512, NQKV, 2560);
  k_pack_w<<<2048, 256, 0, stream>>>(Wo, Woh, Wol, 2048, 2048, 2048, 0);
  k_gemm2<true><<<dim3(NQKV / 128, 2048 / 128), 256, 0, stream>>>(Ah, Al, Bh, Bl, bias3, QKV,
                                                                  2048, NQKV, 2048);
  k_rope<<<dim3(32, NH + NKV), 256, 0, stream>>>(QKV, ropetab, qph, qpl, kph, kpl);
  k_split_v2<<<dim3(32, NKV), 256, 0, stream>>>(QKV, vph, vpl);
  k_attn<<<dim3(NH, S_LEN / 128), 256, 0, stream>>>(qph, qpl, kph, kpl, vph, vpl, sinks, aoh, aol);
  k_gemm2<false><<<dim3(2048 / 128, 2048 / 128), 256, 0, stream>>>(aoh, aol, Woh, Wol, bo, out,
                                                                   2048, 2048, 2048);
}

// Round 9
// 217.508 us; speedup vs baseline: 1.3865x; 1.3493x over previous
//
#include <hip/hip_runtime.h>
#include <hip/hip_bf16.h>
#include <stdint.h>

typedef unsigned short u16;
typedef unsigned int   u32;

#define S_LEN 2048
#define NQKV  3072
#define NH    32
#define NKV   8
#define SWIN  128
#define NEGV  (-1.0e9f)
#define SCALE_Q 0.35355339059327379f   // 64^-0.25

typedef __attribute__((ext_vector_type(4)))  float  f32x4;
typedef __attribute__((ext_vector_type(16))) float  f32x16;
typedef __attribute__((ext_vector_type(8)))  __bf16 bf16x8;

__device__ __forceinline__ u16 f2bf(float x){
  u32 u = __float_as_uint(x);
  return (u16)((u + 0x7fffu + ((u >> 16) & 1u)) >> 16);   // RNE
}
__device__ __forceinline__ float bf2f(u16 h){
  return __uint_as_float(((u32)h) << 16);
}
__device__ __forceinline__ void split2(float a, float b, u32& hw, u32& lw){
  u16 ha = f2bf(a), hb = f2bf(b);
  u16 la = f2bf(a - bf2f(ha)), lb = f2bf(b - bf2f(hb));
  hw = (u32)ha | ((u32)hb << 16);
  lw = (u32)la | ((u32)lb << 16);
}
__device__ __forceinline__ u32 pk2(float a, float b){
  return (u32)f2bf(a) | ((u32)f2bf(b) << 16);
}
__device__ __forceinline__ f32x4 mfma16(bf16x8 a, bf16x8 b, f32x4 c){
  return __builtin_amdgcn_mfma_f32_16x16x32_bf16(a, b, c, 0, 0, 0);
}
__device__ __forceinline__ f32x16 mfma32(bf16x8 a, bf16x8 b, f32x16 c){
  return __builtin_amdgcn_mfma_f32_32x32x16_bf16(a, b, c, 0, 0, 0);
}

typedef __attribute__((address_space(1))) const unsigned int ga_u32;
typedef __attribute__((address_space(3))) unsigned int       ls_u32;
__device__ __forceinline__ void gl16(const void* g, void* l){
  // direct global->LDS, 16B per lane; LDS dest = wave-uniform base + lane*16
  __builtin_amdgcn_global_load_lds((ga_u32*)g, (ls_u32*)l, 16, 0, 0);
}

// ---------------- prep: rope table [S][32][(cos,sin)] + packed bias[3072] ----
__global__ __launch_bounds__(256) void k_prep(const float* __restrict__ bq,
                                              const float* __restrict__ bk,
                                              const float* __restrict__ bv,
                                              float* __restrict__ ropetab,
                                              float* __restrict__ bias3){
  int id = blockIdx.x * 256 + threadIdx.x;        // S*32 threads
  int t = id >> 5, i = id & 31;
  float e = (i * 2.0f) / 64.0f;
  float base = (float)pow(150000.0, (double)e);
  float invf = 1.0f / base;
  float fr = (float)t * invf;
  ropetab[(size_t)id * 2 + 0] = cosf(fr);
  ropetab[(size_t)id * 2 + 1] = sinf(fr);
  if (id < NQKV){
    float b;
    if (id < 2048) b = bq[id];
    else if (id < 2560) b = bk[id - 2048];
    else b = bv[id - 2560];
    bias3[id] = b;
  }
}

// ---- pack A: fp32 row-major -> plain bf16 [M][K/8][8], 8-group SWIZZLED ----
// granule (r,p) stored at p' = (p&~7) | ((p&7) ^ (r&7)).  Bijective within each
// aligned 8-packet group (same 128B line -> coalescing preserved).  The GEMM's
// LDS read applies the same XOR -> 2-way (free) ds_read_b128 banks.
__global__ __launch_bounds__(256) void k_pack_a(const float* __restrict__ in,
                                                u16* __restrict__ oh, int n8){
  int id = blockIdx.x * 256 + threadIdx.x;
  if (id >= n8) return;
  int r = id >> 8, p = id & 255;              // 256 packets per row
  const float4* src = (const float4*)(in + (size_t)id * 8);
  float4 v0 = src[0], v1 = src[1];
  u32 hw[4];
  hw[0] = pk2(v0.x, v0.y); hw[1] = pk2(v0.z, v0.w);
  hw[2] = pk2(v1.x, v1.y); hw[3] = pk2(v1.z, v1.w);
  int psw = (p & ~7) | ((p & 7) ^ (r & 7));
  size_t o = ((size_t)r * 256 + psw) * 8;
  *(uint4*)(oh + o) = make_uint4(hw[0], hw[1], hw[2], hw[3]);
}

// --------- pack W: fp32 [K][N] (N contig) -> plain bf16 [K/8][NTot][8] ------
__global__ __launch_bounds__(256) void k_pack_w(const float* __restrict__ w,
                                                u16* __restrict__ oh,
                                                int K, int N, int NTot, int nOff){
  int id = blockIdx.x * 256 + threadIdx.x;
  int P = K >> 3;
  if (id >= P * N) return;
  int p = id / N, n = id % N;
  u32 hw[4];
  #pragma unroll
  for (int j = 0; j < 4; ++j){
    float a = w[(size_t)(8 * p + 2 * j) * N + n];
    float b = w[(size_t)(8 * p + 2 * j + 1) * N + n];
    hw[j] = pk2(a, b);
  }
  size_t o = ((size_t)p * NTot + nOff + n) * 8;
  *(uint4*)(oh + o) = make_uint4(hw[0], hw[1], hw[2], hw[3]);
}

// ------ plain-bf16 GEMM: BK=64, dbuf + global_load_lds + counted vmcnt ------
// ARM=true : A packed [M][K/8][8], 8-group source-swizzled (see k_pack_a)
// ARM=false: A packed [K/8][M][8] (attn-output layout, conflict-free natively)
// B packed [K/8][N][8]. 128x128 tile, BK=64, 4 waves (2x2), 16x16x32 MFMA.
// Round-6 schedule (best measured): per step, ds_read(buf) -> lgkmcnt(0) ->
// barrier -> STAGE(t+2->buf) -> 32xMFMA -> vmcnt(8) -> barrier.  Never drains
// vmcnt to 0 in the main loop.
template<bool ARM>
__global__ __launch_bounds__(256, 2) void k_gemm3(const u16* __restrict__ A,
                                                  const u16* __restrict__ B,
                                                  const float* __restrict__ bias,
                                                  float* __restrict__ C,
                                                  int M, int N, int K){
  __shared__ u16 lds[2][2][1024][8];   // 64 KiB: [buf][A,B][granule][8]
  const int tid = threadIdx.x;
  const int lane = tid & 63, wid = tid >> 6;
  const int q = lane & 15, g = lane >> 4;
  const int m0 = blockIdx.y * 128, n0 = blockIdx.x * 128;
  const int wr = wid >> 1, wc = wid & 1;
  const int pkK = K >> 3;

  f32x4 acc[4][4];
  #pragma unroll
  for (int a = 0; a < 4; ++a)
    #pragma unroll
    for (int b = 0; b < 4; ++b)
      #pragma unroll
      for (int r = 0; r < 4; ++r) acc[a][b][r] = 0.0f;

  size_t aoff[4], boff[4];
  #pragma unroll
  for (int c = 0; c < 4; ++c){
    int L = c * 256 + tid;           // granule index 0..1023
    if (ARM){
      int row = L >> 3, pa = L & 7;
      aoff[c] = ((size_t)(m0 + row) * pkK + pa) * 8;
    } else {
      int pa = L >> 7, row = L & 127;
      aoff[c] = ((size_t)pa * M + m0 + row) * 8;
    }
    int pb = L >> 7, col = L & 127;
    boff[c] = ((size_t)pb * N + n0 + col) * 8;
  }
  const size_t astep = ARM ? (size_t)64 : (size_t)64 * M;   // +8 packets / step
  const size_t bstep = (size_t)64 * N;

  const int NT = K >> 6;   // 32

  auto STAGE = [&](int b){
    #pragma unroll
    for (int c = 0; c < 4; ++c){
      int lbase = c * 256 + wid * 64;   // wave-uniform LDS granule base
      gl16(A + aoff[c], &lds[b][0][lbase][0]);
      gl16(B + boff[c], &lds[b][1][lbase][0]);
      aoff[c] += astep; boff[c] += bstep;
    }
  };

  // prologue: tiles 0,1 in flight; drain only tile 0's 8 loads/thread.
  STAGE(0);
  STAGE(1);
  asm volatile("s_waitcnt vmcnt(8)" ::: "memory");
  __builtin_amdgcn_s_barrier();

  int buf = 0;
  for (int t = 0; t < NT; ++t){
    bf16x8 af[4][2], bf[4][2];
    #pragma unroll
    for (int ms = 0; ms < 4; ++ms){
      int row = wr * 64 + ms * 16 + q;
      #pragma unroll
      for (int kk = 0; kk < 2; ++kk){
        int ia = ARM ? (row * 8 + ((4 * kk + g) ^ (row & 7)))
                     : ((4 * kk + g) * 128 + row);
        af[ms][kk] = *(const bf16x8*)&lds[buf][0][ia][0];
      }
    }
    #pragma unroll
    for (int ns = 0; ns < 4; ++ns){
      int col = wc * 64 + ns * 16 + q;
      #pragma unroll
      for (int kk = 0; kk < 2; ++kk){
        int ib = (4 * kk + g) * 128 + col;
        bf[ns][kk] = *(const bf16x8*)&lds[buf][1][ib][0];
      }
    }
    asm volatile("s_waitcnt lgkmcnt(0)" ::: "memory");
    __builtin_amdgcn_sched_barrier(0);
    __builtin_amdgcn_s_barrier();        // buf free for overwrite (all waves)
    if (t + 2 < NT) STAGE(buf);          // tile t+2 into freed buffer

    #pragma unroll
    for (int kk = 0; kk < 2; ++kk)
      #pragma unroll
      for (int ms = 0; ms < 4; ++ms)
        #pragma unroll
        for (int ns = 0; ns < 4; ++ns)
          acc[ms][ns] = mfma16(af[ms][kk], bf[ns][kk], acc[ms][ns]);

    if (t + 2 < NT){
      asm volatile("s_waitcnt vmcnt(8)" ::: "memory");   // tile t+1 landed
      __builtin_amdgcn_s_barrier();
    } else if (t + 1 < NT){
      asm volatile("s_waitcnt vmcnt(0)" ::: "memory");   // last prefetch drain
      __builtin_amdgcn_s_barrier();
    }
    buf ^= 1;
  }

  #pragma unroll
  for (int ns = 0; ns < 4; ++ns){
    int col = n0 + wc * 64 + ns * 16 + q;
    float bb = bias[col];
    #pragma unroll
    for (int ms = 0; ms < 4; ++ms){
      int row = m0 + wr * 64 + ms * 16 + g * 4;
      #pragma unroll
      for (int r = 0; r < 4; ++r)
        C[(size_t)(row + r) * N + col] = acc[ms][ns][r] + bb;
    }
  }
}

// -------- fused RoPE+scale+split for q AND k: out [h*8][S][8] hi/lo ---------
// grid (S/64, NH+NKV): blockIdx.y < NH -> q head; else k head
__global__ __launch_bounds__(256) void k_rope(const float* __restrict__ qkv,
                                              const float* __restrict__ tab,
                                              u16* __restrict__ qoh, u16* __restrict__ qol,
                                              u16* __restrict__ koh, u16* __restrict__ kol){
  const int sL = threadIdx.x & 63, tp = threadIdx.x >> 6;
  const int s = blockIdx.x * 64 + sL;
  int h = blockIdx.y;
  u16* oh; u16* ol; int srcOff;
  if (h < NH){ oh = qoh; ol = qol; srcOff = h * 64; }
  else       { h -= NH; oh = koh; ol = kol; srcOff = 2048 + h * 64; }
  const float4* src = (const float4*)(qkv + (size_t)s * NQKV + srcOff + tp * 16);
  const float4* tb  = (const float4*)(tab + (size_t)s * 64 + tp * 16);
  float xv[16], tv[16];
  #pragma unroll
  for (int i = 0; i < 4; ++i){
    float4 a = src[i]; float4 b = tb[i];
    xv[4*i+0]=a.x; xv[4*i+1]=a.y; xv[4*i+2]=a.z; xv[4*i+3]=a.w;
    tv[4*i+0]=b.x; tv[4*i+1]=b.y; tv[4*i+2]=b.z; tv[4*i+3]=b.w;
  }
  u32 hw[8], lw[8];
  #pragma unroll
  for (int j = 0; j < 8; ++j){
    float e = xv[2*j], o = xv[2*j+1];
    float c = tv[2*j], sn = tv[2*j+1];
    float f0 = (e * c - o * sn) * SCALE_Q;
    float f1 = (o * c + e * sn) * SCALE_Q;
    split2(f0, f1, hw[j], lw[j]);
  }
  size_t o0 = ((size_t)(h * 8 + tp * 2 + 0) * S_LEN + s) * 8;
  size_t o1 = ((size_t)(h * 8 + tp * 2 + 1) * S_LEN + s) * 8;
  *(uint4*)(oh + o0) = make_uint4(hw[0], hw[1], hw[2], hw[3]);
  *(uint4*)(oh + o1) = make_uint4(hw[4], hw[5], hw[6], hw[7]);
  *(uint4*)(ol + o0) = make_uint4(lw[0], lw[1], lw[2], lw[3]);
  *(uint4*)(ol + o1) = make_uint4(lw[4], lw[5], lw[6], lw[7]);
}

// ---------------- split V transposed: out [NKV][S/8][64][8], LDS-bounced ----
// grid (S/64, NKV)
__global__ __launch_bounds__(256) void k_split_v2(const float* __restrict__ qkv,
                                                  u16* __restrict__ oh, u16* __restrict__ ol){
  __shared__ float tile[64][65];
  const int h = blockIdx.y;
  const int s0 = blockIdx.x * 64;
  {
    const int sL = threadIdx.x >> 2, ch = threadIdx.x & 3;
    const float4* rp = (const float4*)(qkv + (size_t)(s0 + sL) * NQKV + 2560 + h * 64 + ch * 16);
    #pragma unroll
    for (int i = 0; i < 4; ++i){
      float4 w = rp[i];
      tile[sL][ch * 16 + i * 4 + 0] = w.x;
      tile[sL][ch * 16 + i * 4 + 1] = w.y;
      tile[sL][ch * 16 + i * 4 + 2] = w.z;
      tile[sL][ch * 16 + i * 4 + 3] = w.w;
    }
  }
  __syncthreads();
  const int d = threadIdx.x & 63, spg = threadIdx.x >> 6;
  #pragma unroll
  for (int sp2 = 0; sp2 < 2; ++sp2){
    int spl = spg * 2 + sp2;
    float v[8];
    #pragma unroll
    for (int j = 0; j < 8; ++j) v[j] = tile[spl * 8 + j][d];
    u32 hw[4], lw[4];
    #pragma unroll
    for (int j = 0; j < 4; ++j) split2(v[2*j], v[2*j+1], hw[j], lw[j]);
    size_t o_ = (((size_t)h * 256 + blockIdx.x * 8 + spl) * 64 + d) * 8;
    *(uint4*)(oh + o_) = make_uint4(hw[0], hw[1], hw[2], hw[3]);
    *(uint4*)(ol + o_) = make_uint4(lw[0], lw[1], lw[2], lw[3]);
  }
}

// ---------------- banded attention with sink (flash, swapped QK^T) ----------
// internals split-bf16 (unchanged); epilogue writes PLAIN bf16 [K/8][S][8].
__global__ __launch_bounds__(256) void k_attn(const u16* __restrict__ qh, const u16* __restrict__ ql,
                                              const u16* __restrict__ kh, const u16* __restrict__ kl,
                                              const u16* __restrict__ vh, const u16* __restrict__ vl,
                                              const float* __restrict__ sinks,
                                              u16* __restrict__ aoh){
  const int lane = threadIdx.x & 63;
  const int wid = threadIdx.x >> 6;
  const int h = blockIdx.x;
  const int hkv = h >> 2;
  const int q0 = blockIdx.y * 128 + wid * 32;
  const int lq = lane & 31;
  const int half = lane >> 5;
  const int qi = q0 + lq;

  bf16x8 qfh[4], qfl[4];
  #pragma unroll
  for (int st = 0; st < 4; ++st){
    size_t off = (((size_t)h * 8 + st * 2 + half) * S_LEN + qi) * 8;
    qfh[st] = *(const bf16x8*)(qh + off);
    qfl[st] = *(const bf16x8*)(ql + off);
  }
  float m = sinks[h];
  float lsum = 1.0f;
  f32x16 o0, o1;
  #pragma unroll
  for (int r = 0; r < 16; ++r){ o0[r] = 0.0f; o1[r] = 0.0f; }

  const int kb0 = q0 - 128;
  for (int c = 0; c < 9; ++c){
    const int kb = kb0 + c * 32;
    if (kb + 32 <= 0 || kb >= S_LEN) continue;
    const int keyr = kb + lq;
    const int keyc = min(max(keyr, 0), S_LEN - 1);
    f32x16 sc;
    #pragma unroll
    for (int r = 0; r < 16; ++r) sc[r] = 0.0f;
    #pragma unroll
    for (int st = 0; st < 4; ++st){
      size_t ko = (((size_t)hkv * 8 + st * 2 + half) * S_LEN + keyc) * 8;
      bf16x8 kfh = *(const bf16x8*)(kh + ko);
      bf16x8 kfl = *(const bf16x8*)(kl + ko);
      sc = mfma32(kfh, qfh[st], sc);
      sc = mfma32(kfh, qfl[st], sc);
      sc = mfma32(kfl, qfh[st], sc);
    }
    float tmax = -3.0e38f;
    #pragma unroll
    for (int r = 0; r < 16; ++r){
      int key = kb + (r & 3) + 8 * (r >> 2) + 4 * half;
      int dd = qi - key; if (dd < 0) dd = -dd;
      bool ok = (key >= 0) && (key < S_LEN) && (dd <= SWIN);
      sc[r] = ok ? sc[r] : NEGV;
      tmax = fmaxf(tmax, sc[r]);
    }
    tmax = fmaxf(tmax, __shfl_xor(tmax, 32));
    float mn = fmaxf(m, tmax);
    float alpha = __expf(m - mn);
    m = mn;
    float p[16]; float ps = 0.0f;
    #pragma unroll
    for (int r = 0; r < 16; ++r){ p[r] = __expf(sc[r] - mn); ps += p[r]; }
    ps += __shfl_xor(ps, 32);
    lsum = lsum * alpha + ps;
    #pragma unroll
    for (int r = 0; r < 16; ++r){ o0[r] *= alpha; o1[r] *= alpha; }
    u32 wh[8], wl[8];
    #pragma unroll
    for (int j = 0; j < 8; ++j) split2(p[2 * j], p[2 * j + 1], wh[j], wl[j]);
    bf16x8 pfh[2], pfl[2];
    #pragma unroll
    for (int ks = 0; ks < 2; ++ks){
      u32 x0 = wh[4 * ks + 0], y0 = wh[4 * ks + 2];
      u32 x1 = wh[4 * ks + 1], y1 = wh[4 * ks + 3];
      u32 sx0 = __shfl_xor(x0, 32), sy0 = __shfl_xor(y0, 32);
      u32 sx1 = __shfl_xor(x1, 32), sy1 = __shfl_xor(y1, 32);
      union { u32 u[4]; bf16x8 b; } fb;
      fb.u[0] = half ? sy0 : x0;
      fb.u[1] = half ? sy1 : x1;
      fb.u[2] = half ? y0 : sx0;
      fb.u[3] = half ? y1 : sx1;
      pfh[ks] = fb.b;
      u32 a0 = wl[4 * ks + 0], b0 = wl[4 * ks + 2];
      u32 a1 = wl[4 * ks + 1], b1 = wl[4 * ks + 3];
      u32 sa0 = __shfl_xor(a0, 32), sb0 = __shfl_xor(b0, 32);
      u32 sa1 = __shfl_xor(a1, 32), sb1 = __shfl_xor(b1, 32);
      fb.u[0] = half ? sb0 : a0;
      fb.u[1] = half ? sb1 : a1;
      fb.u[2] = half ? b0 : sa0;
      fb.u[3] = half ? b1 : sa1;
      pfl[ks] = fb.b;
    }
    #pragma unroll
    for (int ks = 0; ks < 2; ++ks){
      int kp = kb / 8 + ks * 2 + half;
      kp = min(max(kp, 0), S_LEN / 8 - 1);
      #pragma unroll
      for (int nt = 0; nt < 2; ++nt){
        size_t vo = (((size_t)hkv * 256 + kp) * 64 + nt * 32 + lq) * 8;
        bf16x8 vfh = *(const bf16x8*)(vh + vo);
        bf16x8 vfl = *(const bf16x8*)(vl + vo);
        f32x16 acc = (nt == 0) ? o0 : o1;
        acc = mfma32(vfh, pfh[ks], acc);
        acc = mfma32(vfh, pfl[ks], acc);
        acc = mfma32(vfl, pfh[ks], acc);
        if (nt == 0) o0 = acc; else o1 = acc;
      }
    }
  }
  float inv = 1.0f / lsum;
  #pragma unroll
  for (int nt = 0; nt < 2; ++nt){
    f32x16 o = (nt == 0) ? o0 : o1;
    #pragma unroll
    for (int rr = 0; rr < 4; ++rr){
      int d0 = nt * 32 + 8 * rr + 4 * half;
      float v0 = o[rr * 4 + 0] * inv, v1 = o[rr * 4 + 1] * inv;
      float v2 = o[rr * 4 + 2] * inv, v3 = o[rr * 4 + 3] * inv;
      int kp_ = h * 8 + nt * 4 + rr;
      size_t oo = ((size_t)kp_ * S_LEN + qi) * 8 + (d0 & 7);
      uint2 wv; wv.x = pk2(v0, v1); wv.y = pk2(v2, v3);
      *(uint2*)(aoh + oo) = wv;
    }
  }
}

// ---------------------------------------------------------------------------
extern "C" void kernel_launch(void* const* d_in, const int* in_sizes, int n_in,
                              void* d_out, int out_size, void* d_ws, size_t ws_size,
                              hipStream_t stream){
  const float* hid = (const float*)d_in[0];
  const float* Wq  = (const float*)d_in[1];
  const float* bq  = (const float*)d_in[2];
  const float* Wk  = (const float*)d_in[3];
  const float* bk  = (const float*)d_in[4];
  const float* Wv  = (const float*)d_in[5];
  const float* bv  = (const float*)d_in[6];
  const float* Wo  = (const float*)d_in[7];
  const float* bo  = (const float*)d_in[8];
  const float* sinks = (const float*)d_in[9];
  float* out = (float*)d_out;

  char* w = (char*)d_ws;
  size_t off = 0;
  auto alloc = [&](size_t bytes){ void* p = w + off; off += (bytes + 255) & ~(size_t)255; return p; };
  float* ropetab = (float*)alloc((size_t)S_LEN * 32 * 2 * 4);
  float* bias3   = (float*)alloc((size_t)NQKV * 4);
  u16* Ah  = (u16*)alloc((size_t)2048 * 2048 * 2);        // hidden bf16 [M][K/8][8] swz8
  u16* Bh  = (u16*)alloc((size_t)256 * NQKV * 8 * 2);     // Wq|Wk|Wv bf16 [K/8][N][8]
  float* QKV = (float*)alloc((size_t)S_LEN * NQKV * 4);
  u16* qph = (u16*)alloc((size_t)NH * 8 * S_LEN * 8 * 2);
  u16* qpl = (u16*)alloc((size_t)NH * 8 * S_LEN * 8 * 2);
  u16* kph = (u16*)alloc((size_t)NKV * 8 * S_LEN * 8 * 2);
  u16* kpl = (u16*)alloc((size_t)NKV * 8 * S_LEN * 8 * 2);
  u16* vph = (u16*)alloc((size_t)NKV * 256 * 64 * 8 * 2);
  u16* vpl = (u16*)alloc((size_t)NKV * 256 * 64 * 8 * 2);
  u16* aoh = (u16*)alloc((size_t)256 * S_LEN * 8 * 2);    // attn out bf16 [K/8][S][8]
  u16* Woh = (u16*)alloc((size_t)256 * 2048 * 8 * 2);     // Wo bf16 [K/8][N][8]
  (void)in_sizes; (void)n_in; (void)out_size; (void)ws_size;

  k_prep<<<256, 256, 0, stream>>>(bq, bk, bv, ropetab, bias3);
  k_pack_a<<<2048, 256, 0, stream>>>(hid, Ah, 2048 * 256);
  k_pack_w<<<2048, 256, 0, stream>>>(Wq, Bh, 2048, 2048, NQKV, 0);
  k_pack_w<<<512, 256, 0, stream>>>(Wk, Bh, 2048, 512, NQKV, 2048);
  k_pack_w<<<512, 256, 0, stream>>>(Wv, Bh, 2048, 512, NQKV, 2560);
  k_pack_w<<<2048, 256, 0, stream>>>(Wo, Woh, 2048, 2048, 2048, 0);
  k_gemm3<true><<<dim3(NQKV / 128, 2048 / 128), 256, 0, stream>>>(Ah, Bh, bias3, QKV,
                                                                  2048, NQKV, 2048);
  k_rope<<<dim3(32, NH + NKV), 256, 0, stream>>>(QKV, ropetab, qph, qpl, kph, kpl);
  k_split_v2<<<dim3(32, NKV), 256, 0, stream>>>(QKV, vph, vpl);
  k_attn<<<dim3(NH, S_LEN / 128), 256, 0, stream>>>(qph, qpl, kph, kpl, vph, vpl, sinks, aoh);
  k_gemm3<false><<<dim3(2048 / 128, 2048 / 128), 256, 0, stream>>>(aoh, Woh, bo, out,
                                                                   2048, 2048, 2048);
}

// Round 10
// 201.813 us; speedup vs baseline: 1.4943x; 1.0778x over previous
//
#include <hip/hip_runtime.h>
#include <hip/hip_bf16.h>
#include <stdint.h>

typedef unsigned short u16;
typedef unsigned int   u32;

#define S_LEN 2048
#define NQKV  3072
#define NH    32
#define NKV   8
#define SWIN  128
#define NEGV  (-1.0e9f)
#define SCALE_Q 0.35355339059327379f   // 64^-0.25

typedef __attribute__((ext_vector_type(4)))  float  f32x4;
typedef __attribute__((ext_vector_type(16))) float  f32x16;
typedef __attribute__((ext_vector_type(8)))  __bf16 bf16x8;

__device__ __forceinline__ u16 f2bf(float x){
  u32 u = __float_as_uint(x);
  return (u16)((u + 0x7fffu + ((u >> 16) & 1u)) >> 16);   // RNE
}
__device__ __forceinline__ u32 pk2(float a, float b){
  return (u32)f2bf(a) | ((u32)f2bf(b) << 16);
}
__device__ __forceinline__ f32x4 mfma16(bf16x8 a, bf16x8 b, f32x4 c){
  return __builtin_amdgcn_mfma_f32_16x16x32_bf16(a, b, c, 0, 0, 0);
}
__device__ __forceinline__ f32x16 mfma32(bf16x8 a, bf16x8 b, f32x16 c){
  return __builtin_amdgcn_mfma_f32_32x32x16_bf16(a, b, c, 0, 0, 0);
}

typedef __attribute__((address_space(1))) const unsigned int ga_u32;
typedef __attribute__((address_space(3))) unsigned int       ls_u32;
__device__ __forceinline__ void gl16(const void* g, void* l){
  // direct global->LDS, 16B per lane; LDS dest = wave-uniform base + lane*16
  __builtin_amdgcn_global_load_lds((ga_u32*)g, (ls_u32*)l, 16, 0, 0);
}

// ---------------- prep: rope table [S][32][(cos,sin)] + packed bias[3072] ----
__global__ __launch_bounds__(256) void k_prep(const float* __restrict__ bq,
                                              const float* __restrict__ bk,
                                              const float* __restrict__ bv,
                                              float* __restrict__ ropetab,
                                              float* __restrict__ bias3){
  int id = blockIdx.x * 256 + threadIdx.x;        // S*32 threads
  int t = id >> 5, i = id & 31;
  float e = (i * 2.0f) / 64.0f;
  float base = (float)pow(150000.0, (double)e);
  float invf = 1.0f / base;
  float fr = (float)t * invf;
  ropetab[(size_t)id * 2 + 0] = cosf(fr);
  ropetab[(size_t)id * 2 + 1] = sinf(fr);
  if (id < NQKV){
    float b;
    if (id < 2048) b = bq[id];
    else if (id < 2560) b = bk[id - 2048];
    else b = bv[id - 2560];
    bias3[id] = b;
  }
}

// -------- fused packing: A (swizzled) + Wq|Wk|Wv -> Bh + Wo -> Woh ----------
// block ranges: [0,2048) A; [2048,4096) Wq; [4096,4608) Wk; [4608,5120) Wv;
// [5120,7168) Wo.  One granule (8 elems) per thread.
__device__ __forceinline__ void packw_seg(const float* __restrict__ w,
                                          u16* __restrict__ oh,
                                          int N, int NTot, int nOff, int id){
  int p = id / N, n = id % N;     // N is a literal at each call site -> shifts
  u32 hw[4];
  #pragma unroll
  for (int j = 0; j < 4; ++j){
    float a = w[(size_t)(8 * p + 2 * j) * N + n];
    float b = w[(size_t)(8 * p + 2 * j + 1) * N + n];
    hw[j] = pk2(a, b);
  }
  size_t o = ((size_t)p * NTot + nOff + n) * 8;
  *(uint4*)(oh + o) = make_uint4(hw[0], hw[1], hw[2], hw[3]);
}
__global__ __launch_bounds__(256) void k_packall(const float* __restrict__ hid,
                                                 const float* __restrict__ Wq,
                                                 const float* __restrict__ Wk,
                                                 const float* __restrict__ Wv,
                                                 const float* __restrict__ Wo,
                                                 u16* __restrict__ Ah,
                                                 u16* __restrict__ Bh,
                                                 u16* __restrict__ Woh){
  int b = blockIdx.x;
  if (b < 2048){
    // A: fp32 row-major -> bf16 [M][K/8][8], 8-group swizzle p'=(p&~7)|((p&7)^(r&7))
    int id = b * 256 + threadIdx.x;
    int r = id >> 8, p = id & 255;
    const float4* src = (const float4*)(hid + (size_t)id * 8);
    float4 v0 = src[0], v1 = src[1];
    u32 hw[4];
    hw[0] = pk2(v0.x, v0.y); hw[1] = pk2(v0.z, v0.w);
    hw[2] = pk2(v1.x, v1.y); hw[3] = pk2(v1.z, v1.w);
    int psw = (p & ~7) | ((p & 7) ^ (r & 7));
    size_t o = ((size_t)r * 256 + psw) * 8;
    *(uint4*)(Ah + o) = make_uint4(hw[0], hw[1], hw[2], hw[3]);
  } else if (b < 4096){
    packw_seg(Wq, Bh, 2048, NQKV, 0,    (b - 2048) * 256 + threadIdx.x);
  } else if (b < 4608){
    packw_seg(Wk, Bh, 512,  NQKV, 2048, (b - 4096) * 256 + threadIdx.x);
  } else if (b < 5120){
    packw_seg(Wv, Bh, 512,  NQKV, 2560, (b - 4608) * 256 + threadIdx.x);
  } else {
    packw_seg(Wo, Woh, 2048, 2048, 0,   (b - 5120) * 256 + threadIdx.x);
  }
}

// ------ plain-bf16 GEMM: BK=64, dbuf + global_load_lds + counted vmcnt ------
// ARM=true : A packed [M][K/8][8], 8-group source-swizzled (see k_packall)
// ARM=false: A packed [K/8][M][8] (attn-output layout, conflict-free natively)
// B packed [K/8][N][8]. 128x128 tile, BK=64, 4 waves (2x2), 16x16x32 MFMA.
// Round-6 schedule (best measured): per step, ds_read(buf) -> lgkmcnt(0) ->
// barrier -> STAGE(t+2->buf) -> 32xMFMA -> vmcnt(8) -> barrier.
template<bool ARM>
__global__ __launch_bounds__(256, 2) void k_gemm3(const u16* __restrict__ A,
                                                  const u16* __restrict__ B,
                                                  const float* __restrict__ bias,
                                                  float* __restrict__ C,
                                                  int M, int N, int K){
  __shared__ u16 lds[2][2][1024][8];   // 64 KiB: [buf][A,B][granule][8]
  const int tid = threadIdx.x;
  const int lane = tid & 63, wid = tid >> 6;
  const int q = lane & 15, g = lane >> 4;
  const int m0 = blockIdx.y * 128, n0 = blockIdx.x * 128;
  const int wr = wid >> 1, wc = wid & 1;
  const int pkK = K >> 3;

  f32x4 acc[4][4];
  #pragma unroll
  for (int a = 0; a < 4; ++a)
    #pragma unroll
    for (int b = 0; b < 4; ++b)
      #pragma unroll
      for (int r = 0; r < 4; ++r) acc[a][b][r] = 0.0f;

  size_t aoff[4], boff[4];
  #pragma unroll
  for (int c = 0; c < 4; ++c){
    int L = c * 256 + tid;           // granule index 0..1023
    if (ARM){
      int row = L >> 3, pa = L & 7;
      aoff[c] = ((size_t)(m0 + row) * pkK + pa) * 8;
    } else {
      int pa = L >> 7, row = L & 127;
      aoff[c] = ((size_t)pa * M + m0 + row) * 8;
    }
    int pb = L >> 7, col = L & 127;
    boff[c] = ((size_t)pb * N + n0 + col) * 8;
  }
  const size_t astep = ARM ? (size_t)64 : (size_t)64 * M;   // +8 packets / step
  const size_t bstep = (size_t)64 * N;

  const int NT = K >> 6;   // 32

  auto STAGE = [&](int b){
    #pragma unroll
    for (int c = 0; c < 4; ++c){
      int lbase = c * 256 + wid * 64;   // wave-uniform LDS granule base
      gl16(A + aoff[c], &lds[b][0][lbase][0]);
      gl16(B + boff[c], &lds[b][1][lbase][0]);
      aoff[c] += astep; boff[c] += bstep;
    }
  };

  // prologue: tiles 0,1 in flight; drain only tile 0's 8 loads/thread.
  STAGE(0);
  STAGE(1);
  asm volatile("s_waitcnt vmcnt(8)" ::: "memory");
  __builtin_amdgcn_s_barrier();

  int buf = 0;
  for (int t = 0; t < NT; ++t){
    bf16x8 af[4][2], bf[4][2];
    #pragma unroll
    for (int ms = 0; ms < 4; ++ms){
      int row = wr * 64 + ms * 16 + q;
      #pragma unroll
      for (int kk = 0; kk < 2; ++kk){
        int ia = ARM ? (row * 8 + ((4 * kk + g) ^ (row & 7)))
                     : ((4 * kk + g) * 128 + row);
        af[ms][kk] = *(const bf16x8*)&lds[buf][0][ia][0];
      }
    }
    #pragma unroll
    for (int ns = 0; ns < 4; ++ns){
      int col = wc * 64 + ns * 16 + q;
      #pragma unroll
      for (int kk = 0; kk < 2; ++kk){
        int ib = (4 * kk + g) * 128 + col;
        bf[ns][kk] = *(const bf16x8*)&lds[buf][1][ib][0];
      }
    }
    asm volatile("s_waitcnt lgkmcnt(0)" ::: "memory");
    __builtin_amdgcn_sched_barrier(0);
    __builtin_amdgcn_s_barrier();        // buf free for overwrite (all waves)
    if (t + 2 < NT) STAGE(buf);          // tile t+2 into freed buffer

    #pragma unroll
    for (int kk = 0; kk < 2; ++kk)
      #pragma unroll
      for (int ms = 0; ms < 4; ++ms)
        #pragma unroll
        for (int ns = 0; ns < 4; ++ns)
          acc[ms][ns] = mfma16(af[ms][kk], bf[ns][kk], acc[ms][ns]);

    if (t + 2 < NT){
      asm volatile("s_waitcnt vmcnt(8)" ::: "memory");   // tile t+1 landed
      __builtin_amdgcn_s_barrier();
    } else if (t + 1 < NT){
      asm volatile("s_waitcnt vmcnt(0)" ::: "memory");   // last prefetch drain
      __builtin_amdgcn_s_barrier();
    }
    buf ^= 1;
  }

  #pragma unroll
  for (int ns = 0; ns < 4; ++ns){
    int col = n0 + wc * 64 + ns * 16 + q;
    float bb = bias[col];
    #pragma unroll
    for (int ms = 0; ms < 4; ++ms){
      int row = m0 + wr * 64 + ms * 16 + g * 4;
      #pragma unroll
      for (int r = 0; r < 4; ++r)
        C[(size_t)(row + r) * N + col] = acc[ms][ns][r] + bb;
    }
  }
}

// ----- fused RoPE+scale for q AND k: out plain bf16 [h*8][S][8] -------------
// grid (S/64, NH+NKV): blockIdx.y < NH -> q head; else k head
__global__ __launch_bounds__(256) void k_rope(const float* __restrict__ qkv,
                                              const float* __restrict__ tab,
                                              u16* __restrict__ qoh,
                                              u16* __restrict__ koh){
  const int sL = threadIdx.x & 63, tp = threadIdx.x >> 6;
  const int s = blockIdx.x * 64 + sL;
  int h = blockIdx.y;
  u16* oh; int srcOff;
  if (h < NH){ oh = qoh; srcOff = h * 64; }
  else       { h -= NH; oh = koh; srcOff = 2048 + h * 64; }
  const float4* src = (const float4*)(qkv + (size_t)s * NQKV + srcOff + tp * 16);
  const float4* tb  = (const float4*)(tab + (size_t)s * 64 + tp * 16);
  float xv[16], tv[16];
  #pragma unroll
  for (int i = 0; i < 4; ++i){
    float4 a = src[i]; float4 b = tb[i];
    xv[4*i+0]=a.x; xv[4*i+1]=a.y; xv[4*i+2]=a.z; xv[4*i+3]=a.w;
    tv[4*i+0]=b.x; tv[4*i+1]=b.y; tv[4*i+2]=b.z; tv[4*i+3]=b.w;
  }
  u32 hw[8];
  #pragma unroll
  for (int j = 0; j < 8; ++j){
    float e = xv[2*j], o = xv[2*j+1];
    float c = tv[2*j], sn = tv[2*j+1];
    float f0 = (e * c - o * sn) * SCALE_Q;
    float f1 = (o * c + e * sn) * SCALE_Q;
    hw[j] = pk2(f0, f1);
  }
  size_t o0 = ((size_t)(h * 8 + tp * 2 + 0) * S_LEN + s) * 8;
  size_t o1 = ((size_t)(h * 8 + tp * 2 + 1) * S_LEN + s) * 8;
  *(uint4*)(oh + o0) = make_uint4(hw[0], hw[1], hw[2], hw[3]);
  *(uint4*)(oh + o1) = make_uint4(hw[4], hw[5], hw[6], hw[7]);
}

// ------- split V transposed: out plain bf16 [NKV][S/8][64][8], LDS-bounced --
// grid (S/64, NKV)
__global__ __launch_bounds__(256) void k_split_v2(const float* __restrict__ qkv,
                                                  u16* __restrict__ oh){
  __shared__ float tile[64][65];
  const int h = blockIdx.y;
  const int s0 = blockIdx.x * 64;
  {
    const int sL = threadIdx.x >> 2, ch = threadIdx.x & 3;
    const float4* rp = (const float4*)(qkv + (size_t)(s0 + sL) * NQKV + 2560 + h * 64 + ch * 16);
    #pragma unroll
    for (int i = 0; i < 4; ++i){
      float4 w = rp[i];
      tile[sL][ch * 16 + i * 4 + 0] = w.x;
      tile[sL][ch * 16 + i * 4 + 1] = w.y;
      tile[sL][ch * 16 + i * 4 + 2] = w.z;
      tile[sL][ch * 16 + i * 4 + 3] = w.w;
    }
  }
  __syncthreads();
  const int d = threadIdx.x & 63, spg = threadIdx.x >> 6;
  #pragma unroll
  for (int sp2 = 0; sp2 < 2; ++sp2){
    int spl = spg * 2 + sp2;
    float v[8];
    #pragma unroll
    for (int j = 0; j < 8; ++j) v[j] = tile[spl * 8 + j][d];
    u32 hw[4];
    #pragma unroll
    for (int j = 0; j < 4; ++j) hw[j] = pk2(v[2*j], v[2*j+1]);
    size_t o_ = (((size_t)h * 256 + blockIdx.x * 8 + spl) * 64 + d) * 8;
    *(uint4*)(oh + o_) = make_uint4(hw[0], hw[1], hw[2], hw[3]);
  }
}

// -------- banded attention with sink (flash, swapped QK^T, PLAIN bf16) ------
// QK^T: 4 mfma32/tile; PV: 4 mfma32/tile.  P -> bf16 via pk2 (no split).
__global__ __launch_bounds__(256) void k_attn(const u16* __restrict__ qh,
                                              const u16* __restrict__ kh,
                                              const u16* __restrict__ vh,
                                              const float* __restrict__ sinks,
                                              u16* __restrict__ aoh){
  const int lane = threadIdx.x & 63;
  const int wid = threadIdx.x >> 6;
  const int h = blockIdx.x;
  const int hkv = h >> 2;
  const int q0 = blockIdx.y * 128 + wid * 32;
  const int lq = lane & 31;
  const int half = lane >> 5;
  const int qi = q0 + lq;

  bf16x8 qf[4];
  #pragma unroll
  for (int st = 0; st < 4; ++st){
    size_t off = (((size_t)h * 8 + st * 2 + half) * S_LEN + qi) * 8;
    qf[st] = *(const bf16x8*)(qh + off);
  }
  float m = sinks[h];       // sink folded into online softmax: m0=sink, l0=1
  float lsum = 1.0f;
  f32x16 o0, o1;
  #pragma unroll
  for (int r = 0; r < 16; ++r){ o0[r] = 0.0f; o1[r] = 0.0f; }

  const int kb0 = q0 - 128;
  for (int c = 0; c < 9; ++c){
    const int kb = kb0 + c * 32;
    if (kb + 32 <= 0 || kb >= S_LEN) continue;
    const int keyr = kb + lq;
    const int keyc = min(max(keyr, 0), S_LEN - 1);
    f32x16 sc;
    #pragma unroll
    for (int r = 0; r < 16; ++r) sc[r] = 0.0f;
    #pragma unroll
    for (int st = 0; st < 4; ++st){
      size_t ko = (((size_t)hkv * 8 + st * 2 + half) * S_LEN + keyc) * 8;
      bf16x8 kf = *(const bf16x8*)(kh + ko);
      sc = mfma32(kf, qf[st], sc);
    }
    float tmax = -3.0e38f;
    #pragma unroll
    for (int r = 0; r < 16; ++r){
      int key = kb + (r & 3) + 8 * (r >> 2) + 4 * half;
      int dd = qi - key; if (dd < 0) dd = -dd;
      bool ok = (key >= 0) && (key < S_LEN) && (dd <= SWIN);
      sc[r] = ok ? sc[r] : NEGV;
      tmax = fmaxf(tmax, sc[r]);
    }
    tmax = fmaxf(tmax, __shfl_xor(tmax, 32));
    float mn = fmaxf(m, tmax);
    float alpha = __expf(m - mn);
    m = mn;
    float p[16]; float ps = 0.0f;
    #pragma unroll
    for (int r = 0; r < 16; ++r){ p[r] = __expf(sc[r] - mn); ps += p[r]; }
    ps += __shfl_xor(ps, 32);
    lsum = lsum * alpha + ps;
    #pragma unroll
    for (int r = 0; r < 16; ++r){ o0[r] *= alpha; o1[r] *= alpha; }
    // P -> bf16 and build P^T fragments via half-exchange (hi only)
    u32 wh[8];
    #pragma unroll
    for (int j = 0; j < 8; ++j) wh[j] = pk2(p[2 * j], p[2 * j + 1]);
    bf16x8 pfh[2];
    #pragma unroll
    for (int ks = 0; ks < 2; ++ks){
      u32 x0 = wh[4 * ks + 0], y0 = wh[4 * ks + 2];
      u32 x1 = wh[4 * ks + 1], y1 = wh[4 * ks + 3];
      u32 sx0 = __shfl_xor(x0, 32), sy0 = __shfl_xor(y0, 32);
      u32 sx1 = __shfl_xor(x1, 32), sy1 = __shfl_xor(y1, 32);
      union { u32 u[4]; bf16x8 b; } fb;
      fb.u[0] = half ? sy0 : x0;
      fb.u[1] = half ? sy1 : x1;
      fb.u[2] = half ? y0 : sx0;
      fb.u[3] = half ? y1 : sx1;
      pfh[ks] = fb.b;
    }
    #pragma unroll
    for (int ks = 0; ks < 2; ++ks){
      int kp = kb / 8 + ks * 2 + half;
      kp = min(max(kp, 0), S_LEN / 8 - 1);
      #pragma unroll
      for (int nt = 0; nt < 2; ++nt){
        size_t vo = (((size_t)hkv * 256 + kp) * 64 + nt * 32 + lq) * 8;
        bf16x8 vf = *(const bf16x8*)(vh + vo);
        f32x16 acc = (nt == 0) ? o0 : o1;
        acc = mfma32(vf, pfh[ks], acc);
        if (nt == 0) o0 = acc; else o1 = acc;
      }
    }
  }
  float inv = 1.0f / lsum;
  #pragma unroll
  for (int nt = 0; nt < 2; ++nt){
    f32x16 o = (nt == 0) ? o0 : o1;
    #pragma unroll
    for (int rr = 0; rr < 4; ++rr){
      int d0 = nt * 32 + 8 * rr + 4 * half;
      float v0 = o[rr * 4 + 0] * inv, v1 = o[rr * 4 + 1] * inv;
      float v2 = o[rr * 4 + 2] * inv, v3 = o[rr * 4 + 3] * inv;
      int kp_ = h * 8 + nt * 4 + rr;
      size_t oo = ((size_t)kp_ * S_LEN + qi) * 8 + (d0 & 7);
      uint2 wv; wv.x = pk2(v0, v1); wv.y = pk2(v2, v3);
      *(uint2*)(aoh + oo) = wv;
    }
  }
}

// ---------------------------------------------------------------------------
extern "C" void kernel_launch(void* const* d_in, const int* in_sizes, int n_in,
                              void* d_out, int out_size, void* d_ws, size_t ws_size,
                              hipStream_t stream){
  const float* hid = (const float*)d_in[0];
  const float* Wq  = (const float*)d_in[1];
  const float* bq  = (const float*)d_in[2];
  const float* Wk  = (const float*)d_in[3];
  const float* bk  = (const float*)d_in[4];
  const float* Wv  = (const float*)d_in[5];
  const float* bv  = (const float*)d_in[6];
  const float* Wo  = (const float*)d_in[7];
  const float* bo  = (const float*)d_in[8];
  const float* sinks = (const float*)d_in[9];
  float* out = (float*)d_out;

  char* w = (char*)d_ws;
  size_t off = 0;
  auto alloc = [&](size_t bytes){ void* p = w + off; off += (bytes + 255) & ~(size_t)255; return p; };
  float* ropetab = (float*)alloc((size_t)S_LEN * 32 * 2 * 4);
  float* bias3   = (float*)alloc((size_t)NQKV * 4);
  u16* Ah  = (u16*)alloc((size_t)2048 * 2048 * 2);        // hidden bf16 [M][K/8][8] swz8
  u16* Bh  = (u16*)alloc((size_t)256 * NQKV * 8 * 2);     // Wq|Wk|Wv bf16 [K/8][N][8]
  float* QKV = (float*)alloc((size_t)S_LEN * NQKV * 4);
  u16* qph = (u16*)alloc((size_t)NH * 8 * S_LEN * 8 * 2);
  u16* kph = (u16*)alloc((size_t)NKV * 8 * S_LEN * 8 * 2);
  u16* vph = (u16*)alloc((size_t)NKV * 256 * 64 * 8 * 2);
  u16* aoh = (u16*)alloc((size_t)256 * S_LEN * 8 * 2);    // attn out bf16 [K/8][S][8]
  u16* Woh = (u16*)alloc((size_t)256 * 2048 * 8 * 2);     // Wo bf16 [K/8][N][8]
  (void)in_sizes; (void)n_in; (void)out_size; (void)ws_size;

  k_prep<<<256, 256, 0, stream>>>(bq, bk, bv, ropetab, bias3);
  k_packall<<<7168, 256, 0, stream>>>(hid, Wq, Wk, Wv, Wo, Ah, Bh, Woh);
  k_gemm3<true><<<dim3(NQKV / 128, 2048 / 128), 256, 0, stream>>>(Ah, Bh, bias3, QKV,
                                                                  2048, NQKV, 2048);
  k_rope<<<dim3(32, NH + NKV), 256, 0, stream>>>(QKV, ropetab, qph, kph);
  k_split_v2<<<dim3(32, NKV), 256, 0, stream>>>(QKV, vph);
  k_attn<<<dim3(NH, S_LEN / 128), 256, 0, stream>>>(qph, kph, vph, sinks, aoh);
  k_gemm3<false><<<dim3(2048 / 128, 2048 / 128), 256, 0, stream>>>(aoh, Woh, bo, out,
                                                                   2048, 2048, 2048);
}